// Round 1
// 418.573 us; speedup vs baseline: 1.3796x; 1.3796x over previous
//
#include <hip/hip_runtime.h>

// EfficientHebbian on MI355X (gfx950) — round 4.
// LN -> xn bf16 ; transpose -> xnT ; G = xnT@xnT^T symmetric-upper, split-16
// (partials in d_out y region) ; reduce mirrors lower triangle.
// trace = 0.9*tr + (1/32)(W@G) fused epilogue ; y = xn@W^T (NT)
// polar: power-iter sigma_max scale + 3 quintic (Muon) + 3 cubic NS.
// All GEMMs: double-buffered prefetch 2-phase (stage(t+1) -> compute(t) ->
// one __syncthreads per K-step) per catalog T3-minimum recipe.

typedef short short4v __attribute__((ext_vector_type(4)));
typedef short short8v __attribute__((ext_vector_type(8)));
typedef unsigned short ushort4v __attribute__((ext_vector_type(4)));
typedef unsigned short ushort8v __attribute__((ext_vector_type(8)));
typedef float f32x4 __attribute__((ext_vector_type(4)));

__device__ __forceinline__ unsigned short f2bf(float f) {
  union { float f; unsigned u; } v; v.f = f;
  unsigned r = 0x7fffu + ((v.u >> 16) & 1u);
  return (unsigned short)((v.u + r) >> 16);
}

__device__ __forceinline__ void gload_lds16(const void* g, void* l) {
  __builtin_amdgcn_global_load_lds(
      (const __attribute__((address_space(1))) void*)g,
      (__attribute__((address_space(3))) void*)l, 16, 0, 0);
}

// ---------------- LayerNorm: x[row][1024] f32 -> xn bf16 ----------------
__global__ void __launch_bounds__(256) ln_kernel(
    const float* __restrict__ x, const float* __restrict__ gamma,
    const float* __restrict__ beta, unsigned short* __restrict__ xn) {
  __shared__ float sb[4];
  const int row = blockIdx.x;
  const int t = threadIdx.x;
  const float* xr = x + (size_t)row * 1024;
  f32x4 v = *(const f32x4*)(xr + t * 4);
  float s = v[0] + v[1] + v[2] + v[3];
  for (int m = 32; m; m >>= 1) s += __shfl_xor(s, m);
  if ((t & 63) == 0) sb[t >> 6] = s;
  __syncthreads();
  float mu = (sb[0] + sb[1] + sb[2] + sb[3]) * (1.0f / 1024.0f);
  __syncthreads();
  f32x4 d; float q = 0.f;
  for (int i = 0; i < 4; i++) { d[i] = v[i] - mu; q += d[i] * d[i]; }
  for (int m = 32; m; m >>= 1) q += __shfl_xor(q, m);
  if ((t & 63) == 0) sb[t >> 6] = q;
  __syncthreads();
  float var = (sb[0] + sb[1] + sb[2] + sb[3]) * (1.0f / 1024.0f);
  float rs = rsqrtf(var + 1e-5f);
  f32x4 g4 = *(const f32x4*)(gamma + t * 4);
  f32x4 b4 = *(const f32x4*)(beta + t * 4);
  ushort4v o;
  for (int i = 0; i < 4; i++) o[i] = f2bf(d[i] * rs * g4[i] + b4[i]);
  *(ushort4v*)(xn + (size_t)row * 1024 + t * 4) = o;
}

// ---------------- f32 -> bf16 convert ----------------
__global__ void __launch_bounds__(256) cvt_kernel(
    const float* __restrict__ in, unsigned short* __restrict__ out) {
  size_t e = ((size_t)blockIdx.x * 256 + threadIdx.x) * 4;
  f32x4 v = *(const f32x4*)(in + e);
  ushort4v o;
  for (int k = 0; k < 4; k++) o[k] = f2bf(v[k]);
  *(ushort4v*)(out + e) = o;
}

// ---------------- bf16 transpose: out[c][r] = in[r][c], 64x64 tiles ----------
__global__ void __launch_bounds__(256) transpose_kernel(
    const unsigned short* __restrict__ in, unsigned short* __restrict__ out,
    int R, int C) {
  __shared__ unsigned short tb[64][65];
  const int t = threadIdx.x;
  const int r0 = blockIdx.x * 64, c0 = blockIdx.y * 64;
#pragma unroll
  for (int p = 0; p < 2; p++) {
    int lr = p * 32 + (t >> 3);
    int lc = (t & 7) * 8;
    ushort8v v = *(const ushort8v*)(in + (size_t)(r0 + lr) * C + c0 + lc);
#pragma unroll
    for (int d = 0; d < 8; d++) tb[lr][lc + d] = v[d];
  }
  __syncthreads();
#pragma unroll
  for (int p = 0; p < 2; p++) {
    int orr = p * 32 + (t >> 3);
    int oc = (t & 7) * 8;
    ushort8v w;
#pragma unroll
    for (int d = 0; d < 8; d++) w[d] = tb[oc + d][orr];
    *(ushort8v*)(out + (size_t)(c0 + orr) * R + r0 + oc) = w;
  }
}

// ---------------- NT GEMM: C[M][N] = A[M][K] @ B[N][K]^T ----------------
// BM x BM tile, BK=64, WM x WN waves. XOR-swizzled LDS via pre-swizzled global
// src. Double-buffered prefetch 2-phase: stage(t+1) issued before compute(t);
// single __syncthreads per K-step drains vmcnt after compute.
// modes: 0: v=acc (+addF if set)
//        1: v = c0*(r==c) + c1*addF + c2*acc        (immediate coeffs)
//        2: v = dcoef[0]*(r==c) + dcoef[1]*addF + dcoef[2]*acc
//        3: v = 0.9*addF + (1/32)*(acc + addF2*dvec[c])   (trace epilogue)
//        4: partial: outF += blockIdx.z<<20 ; k-range = z*Kseg..(z+1)*Kseg
//        5: symmetric-upper partial: blockIdx.x = triangle tile index (i<=j),
//           blockIdx.y = z-seg; outF += z<<20
// outBT (if set, BM=64 only): writes bf16 transposed tile via LDS.
template <int BM, int WM, int WN>
__global__ void __launch_bounds__(WM * WN * 64, BM == 64 ? 4 : 2) gemm_bt_kernel(
    const unsigned short* __restrict__ A, const unsigned short* __restrict__ B,
    const float* __restrict__ addF, const float* __restrict__ addF2,
    const float* __restrict__ dvec, const float* __restrict__ dcoef,
    float* __restrict__ outF, unsigned short* __restrict__ outB,
    unsigned short* __restrict__ outBT,
    int ldk, int Kseg, int mode, float c0, float c1, float c2) {
  constexpr int WAVES = WM * WN;
  constexpr int NT = WAVES * 64;
  constexpr int FMm = BM / (16 * WM);
  constexpr int FMn = BM / (16 * WN);
  constexpr int CPW = BM / (8 * WAVES);  // 1KB chunks per wave per operand
  constexpr int BUFS = 2 * BM * 64;      // shorts per buffer (A then B)
  __shared__ __align__(16) unsigned short lds[2 * BUFS];
  const int tid = threadIdx.x, lane = tid & 63, wv = tid >> 6;
  const int wm = wv / WN, wn = wv % WN;

  int m0, n0, kb = 0, zseg = 0;
  if (mode == 5) {
    const int ntile = 1024 / BM;
    int tt = blockIdx.x, ti = 0;
    while (tt >= ntile - ti) { tt -= ntile - ti; ++ti; }
    m0 = ti * BM; n0 = (ti + tt) * BM;
    zseg = blockIdx.y; kb = zseg * Kseg;
  } else {
    m0 = blockIdx.x * BM; n0 = blockIdx.y * BM;
    if (mode == 4) { zseg = blockIdx.z; kb = zseg * Kseg; }
  }

  const int srow = lane >> 3;
  const int skoff = 8 * ((lane & 7) ^ srow);  // pre-swizzled global k-offset

  f32x4 acc[FMm][FMn];
  for (int a = 0; a < FMm; a++)
    for (int b = 0; b < FMn; b++) acc[a][b] = (f32x4){0.f, 0.f, 0.f, 0.f};

  auto stage = [&](int buf, int kk) {
#pragma unroll
    for (int ci = 0; ci < CPW; ci++) {
      int ch = wv * CPW + ci;
      const unsigned short* ga = A + (size_t)(m0 + 8 * ch + srow) * ldk + kk + skoff;
      const unsigned short* gb = B + (size_t)(n0 + 8 * ch + srow) * ldk + kk + skoff;
      char* lb = (char*)(lds + buf * BUFS);
      gload_lds16(ga, lb + ch * 1024);
      gload_lds16(gb, lb + BM * 128 + ch * 1024);
    }
  };

  const int nk = Kseg >> 6;
  int cur = 0;
  stage(0, kb);
  __syncthreads();

  for (int t = 0; t < nk; ++t) {
    if (t + 1 < nk) stage(cur ^ 1, kb + ((t + 1) << 6));  // prefetch overlaps compute
    const unsigned short* As = lds + cur * BUFS;
    const unsigned short* Bs = As + BM * 64;
    const int g = lane >> 4;
#pragma unroll
    for (int ks = 0; ks < 2; ks++) {
      short8v af[FMm], bfr[FMn];
#pragma unroll
      for (int fm = 0; fm < FMm; fm++) {
        int row = wm * (BM / WM) + fm * 16 + (lane & 15);
        int swz = (row & 7) << 4;
        const char* rp = (const char*)As + row * 128;
        int o = ks * 64 + g * 8;
        short4v lo = *(const short4v*)(rp + (o ^ swz));
        short4v hi = *(const short4v*)(rp + ((o + 32) ^ swz));
        af[fm] = __builtin_shufflevector(lo, hi, 0, 1, 2, 3, 4, 5, 6, 7);
      }
#pragma unroll
      for (int fn = 0; fn < FMn; fn++) {
        int row = wn * (BM / WN) + fn * 16 + (lane & 15);
        int swz = (row & 7) << 4;
        const char* rp = (const char*)Bs + row * 128;
        int o = ks * 64 + g * 8;
        short4v lo = *(const short4v*)(rp + (o ^ swz));
        short4v hi = *(const short4v*)(rp + ((o + 32) ^ swz));
        bfr[fn] = __builtin_shufflevector(lo, hi, 0, 1, 2, 3, 4, 5, 6, 7);
      }
#pragma unroll
      for (int fm = 0; fm < FMm; fm++)
#pragma unroll
        for (int fn = 0; fn < FMn; fn++)
          acc[fm][fn] = __builtin_amdgcn_mfma_f32_16x16x32_bf16(
              af[fm], bfr[fn], acc[fm][fn], 0, 0, 0);
    }
    __syncthreads();  // drains vmcnt(0): prefetched tile ready; buf[cur] free
    cur ^= 1;
  }

  float* of = outF;
  if ((mode == 4 || mode == 5) && of) of += ((size_t)zseg << 20);
  float dc0 = 0.f, dc1 = 0.f, dc2 = 0.f;
  if (mode == 2) { dc0 = dcoef[0]; dc1 = dcoef[1]; dc2 = dcoef[2]; }

#pragma unroll
  for (int fm = 0; fm < FMm; fm++) {
    int r0 = m0 + wm * (BM / WM) + fm * 16 + (lane >> 4) * 4;
#pragma unroll
    for (int fn = 0; fn < FMn; fn++) {
      int c = n0 + wn * (BM / WN) + fn * 16 + (lane & 15);
#pragma unroll
      for (int j = 0; j < 4; j++) {
        int r = r0 + j;
        size_t off = (size_t)r * 1024 + c;
        float v = acc[fm][fn][j];
        if (mode == 0) {
          if (addF) v += addF[off];
        } else if (mode == 1) {
          v = c0 * (r == c ? 1.f : 0.f) + (addF ? c1 * addF[off] : 0.f) + c2 * v;
        } else if (mode == 2) {
          v = dc0 * (r == c ? 1.f : 0.f) + dc1 * addF[off] + dc2 * v;
        } else if (mode == 3) {
          v = 0.9f * addF[off] + 0.03125f * (v + addF2[off] * dvec[c]);
        }
        if (of) of[off] = v;
        if (outB) outB[off] = f2bf(v);
        acc[fm][fn][j] = v;
      }
    }
  }

  // optional transposed bf16 output (used by BM=64 NS X-updates only)
  if (outBT) {
    constexpr int LDT = BM + 1;
    __syncthreads();
#pragma unroll
    for (int fm = 0; fm < FMm; fm++) {
      int lr0 = wm * (BM / WM) + fm * 16 + (lane >> 4) * 4;
#pragma unroll
      for (int fn = 0; fn < FMn; fn++) {
        int lc = wn * (BM / WN) + fn * 16 + (lane & 15);
#pragma unroll
        for (int j = 0; j < 4; j++)
          lds[(lr0 + j) * LDT + lc] = f2bf(acc[fm][fn][j]);
      }
    }
    __syncthreads();
    for (int e = tid * 8; e < BM * BM; e += NT * 8) {
      int orr = e / BM;          // output row = col of tile
      int oc = e % BM;           // output col base = row of tile
      ushort8v w;
#pragma unroll
      for (int d = 0; d < 8; d++) w[d] = lds[(oc + d) * LDT + orr];
      *(ushort8v*)(outBT + (size_t)(n0 + orr) * 1024 + m0 + oc) = w;
    }
  }
}

// ---- reduce G: sum 16 partials over upper 128^2 tiles -> Gb bf16, mirror
// lower triangle, diag zeroed + gdiag. grid: dim3(16 subblocks, 36 tiles).
__global__ void __launch_bounds__(256) reduce_g_kernel(
    const float* __restrict__ P, unsigned short* __restrict__ Gb,
    float* __restrict__ gdiag) {
  int tt = blockIdx.y, ti = 0;
  while (tt >= 8 - ti) { tt -= 8 - ti; ++ti; }
  const int tj = ti + tt;
  const int eloc = (blockIdx.x * 256 + threadIdx.x) * 4;
  const int lr = eloc >> 7, lc = eloc & 127;
  const int r = ti * 128 + lr, c0 = tj * 128 + lc;
  const size_t off = (size_t)r * 1024 + c0;
  f32x4 s = *(const f32x4*)(P + off);
#pragma unroll
  for (int z = 1; z < 16; z++)
    s += *(const f32x4*)(P + ((size_t)z << 20) + off);
  ushort4v o;
#pragma unroll
  for (int q = 0; q < 4; q++) {
    int c = c0 + q;
    unsigned short b = f2bf(s[q]);
    if (ti == tj && c == r) { gdiag[r] = s[q]; o[q] = 0; }
    else o[q] = b;
    if (ti != tj) Gb[(size_t)c * 1024 + r] = b;  // mirror into lower triangle
  }
  *(ushort4v*)(Gb + off) = o;
}

// ---------------- w = weight + 0.01*clip(trace,-1,1); per-column sumsq -------
__global__ void __launch_bounds__(256) wbuild_kernel(
    const float* __restrict__ weight, const float* __restrict__ tout,
    float* __restrict__ w, float* __restrict__ colpart) {
  int t = threadIdx.x, blk = blockIdx.x;
  float cs[4] = {0.f, 0.f, 0.f, 0.f};
  for (int r = 0; r < 64; r++) {
    size_t row = (size_t)blk * 64 + r;
    for (int cc = 0; cc < 4; cc++) {
      size_t idx = row * 1024 + cc * 256 + t;
      float u = tout[idx];
      u = fminf(fmaxf(u, -1.f), 1.f);
      float wv = weight[idx] + 0.01f * u;
      w[idx] = wv;
      cs[cc] += wv * wv;
    }
  }
  for (int cc = 0; cc < 4; cc++) colpart[blk * 1024 + cc * 256 + t] = cs[cc];
}

// ---------------- cscale[j] = 1/max(colnorm_j,1e-3) (no fro) ----------------
__global__ void __launch_bounds__(256) colfin_kernel(
    const float* __restrict__ colpart, float* __restrict__ cscale) {
  int t = threadIdx.x;
  for (int q = 0; q < 4; q++) {
    int j = t * 4 + q;
    float s = 0.f;
    for (int b = 0; b < 16; b++) s += colpart[b * 1024 + j];
    float cn = fmaxf(sqrtf(s), 1e-3f);
    cscale[j] = 1.f / cn;
  }
}

// ---------------- X0 = w * cscale (f32 + bf16) ----------------
__global__ void __launch_bounds__(256) x0_kernel(
    const float* __restrict__ w, const float* __restrict__ cscale,
    float* __restrict__ X, unsigned short* __restrict__ Xb) {
  size_t e = ((size_t)blockIdx.x * 256 + threadIdx.x) * 4;
  int j = (int)(e & 1023);
  f32x4 wv = *(const f32x4*)(w + e);
  f32x4 cs = *(const f32x4*)(cscale + j);
  f32x4 xo; ushort4v xb;
  for (int q = 0; q < 4; q++) { xo[q] = wv[q] * cs[q]; xb[q] = f2bf(xo[q]); }
  *(f32x4*)(X + e) = xo;
  *(ushort4v*)(Xb + e) = xb;
}

// ---------------- power-iteration init: v0 = +/-1 hash; zero norms ----------
__global__ void __launch_bounds__(256) pinit_kernel(
    float* __restrict__ v0, float* __restrict__ norms) {
  int i = blockIdx.x * 256 + threadIdx.x;
  unsigned h = (unsigned)i * 2654435761u;
  v0[i] = ((h >> 16) & 1u) ? 1.f : -1.f;
  if (blockIdx.x == 0 && threadIdx.x < 4) norms[threadIdx.x] = 0.f;
}

// ---------------- matvec: vout = A vin (A f32 1024x1024); ||vout||^2 += norm --
__global__ void __launch_bounds__(256) matvec_kernel(
    const float* __restrict__ A, const float* __restrict__ vin,
    float* __restrict__ vout, float* __restrict__ normsq) {
  __shared__ float red[4];
  int t = threadIdx.x;
  int r0 = blockIdx.x * 16;
  f32x4 vv = *(const f32x4*)(vin + t * 4);
  float sq = 0.f;
  for (int r = 0; r < 16; r++) {
    f32x4 a = *(const f32x4*)(A + (size_t)(r0 + r) * 1024 + t * 4);
    float d = a[0] * vv[0] + a[1] * vv[1] + a[2] * vv[2] + a[3] * vv[3];
    for (int m = 32; m; m >>= 1) d += __shfl_xor(d, m);
    if ((t & 63) == 0) red[t >> 6] = d;
    __syncthreads();
    if (t == 0) {
      float s = red[0] + red[1] + red[2] + red[3];
      vout[r0 + r] = s;
      sq += s * s;
    }
    __syncthreads();
  }
  if (t == 0) atomicAdd(normsq, sq);
}

// ---------------- quintic-1 coefficients from power-iter norms ----------------
__global__ void coefq_kernel(const float* __restrict__ norms,
                             float* __restrict__ dcoef) {
  const float QA = 3.4445f, QB = -4.7750f, QC = 2.0315f;
  float n1 = fmaxf(norms[1], 1e-30f), n2 = fmaxf(norms[2], 1e-30f);
  float lam = sqrtf(n2 / n1);            // ~ sigma_max^2
  float s = sqrtf(fmaxf(lam, 1e-8f)) / 0.95f;
  s = fmaxf(s, 1e-3f);
  float s2 = s * s;
  dcoef[0] = QA / s;
  dcoef[1] = QB / (s * s2);
  dcoef[2] = QC / (s * s2 * s2);
}

extern "C" void kernel_launch(void* const* d_in, const int* in_sizes, int n_in,
                              void* d_out, int out_size, void* d_ws, size_t ws_size,
                              hipStream_t stream) {
  const float* x      = (const float*)d_in[0];
  const float* weight = (const float*)d_in[1];
  const float* gamma  = (const float*)d_in[2];
  const float* beta   = (const float*)d_in[3];
  const float* trace  = (const float*)d_in[4];

  float* y_out = (float*)d_out;                  // [16384,1024]
  float* w_out = y_out + (size_t)16777216;       // [1024,1024]
  float* t_out = w_out + (size_t)1048576;        // [1024,1024]

  const size_t MB = 1048576;
  char* ws = (char*)d_ws;
  unsigned short* xn   = (unsigned short*)(ws);            // 32MB
  unsigned short* xnT  = (unsigned short*)(ws + 32 * MB);  // 32MB
  float* Xf0           = (float*)(ws + 64 * MB);           // 4MB
  float* Xf1           = (float*)(ws + 68 * MB);           // 4MB
  float* wbuf          = (float*)(ws + 72 * MB);           // 4MB (reused as Af)
  float* Af            = (float*)(ws + 72 * MB);           //   alias (wbuf dead)
  unsigned short* Xb0  = (unsigned short*)(ws + 76 * MB);  // 2MB
  unsigned short* Xb1  = (unsigned short*)(ws + 78 * MB);  // 2MB
  unsigned short* XbT0 = (unsigned short*)(ws + 80 * MB);  // 2MB
  unsigned short* XbT1 = (unsigned short*)(ws + 82 * MB);  // 2MB
  unsigned short* Ab   = (unsigned short*)(ws + 84 * MB);  // 2MB
  unsigned short* Rb   = (unsigned short*)(ws + 86 * MB);  // 2MB (also quintic B)
  unsigned short* Gb   = (unsigned short*)(ws + 88 * MB);  // 2MB
  unsigned short* wb   = (unsigned short*)(ws + 90 * MB);  // 2MB
  float* colpart       = (float*)(ws + 92 * MB);           // 64KB
  float* cscale        = (float*)(ws + 92 * MB + 65536);   // 4KB
  float* gdiag         = (float*)(ws + 92 * MB + 69632);   // 4KB
  float* vpow          = (float*)(ws + 92 * MB + 73728);   // 4 x 4KB (v0..v3)
  float* norms         = (float*)(ws + 92 * MB + 90112);   // 64B
  float* dcoef         = (float*)(ws + 92 * MB + 90176);   // 64B

  // G partials live in the (not yet written) y region of d_out: 16 x 4MB = 64MB
  float* P = y_out;

  // 1) LN -> xn ; transpose -> xnT ; weight -> bf16
  ln_kernel<<<16384, 256, 0, stream>>>(x, gamma, beta, xn);
  transpose_kernel<<<dim3(256, 16), 256, 0, stream>>>(xn, xnT, 16384, 1024);
  cvt_kernel<<<1024, 256, 0, stream>>>(weight, wb);

  // 2) G = xnT @ xnT^T symmetric: upper 36 tiles, K=16384 split-16 -> P
  gemm_bt_kernel<128, 2, 2><<<dim3(36, 16), 256, 0, stream>>>(
      xnT, xnT, nullptr, nullptr, nullptr, nullptr, P, nullptr, nullptr,
      16384, 1024, 5, 0.f, 0.f, 0.f);
  reduce_g_kernel<<<dim3(16, 36), 256, 0, stream>>>(P, Gb, gdiag);

  // 3) t_out = 0.9*trace + (1/32)*(W@G)  (diag of G corrected in f32)
  gemm_bt_kernel<64, 4, 2><<<dim3(16, 16), 512, 0, stream>>>(
      wb, Gb, trace, weight, gdiag, nullptr, t_out, nullptr, nullptr,
      1024, 1024, 3, 0.f, 0.f, 0.f);

  // 4) y = xn @ W^T (overwrites P region)
  gemm_bt_kernel<128, 2, 2><<<dim3(128, 8), 256, 0, stream>>>(
      xn, wb, nullptr, nullptr, nullptr, nullptr, y_out, nullptr, nullptr,
      1024, 1024, 0, 0.f, 0.f, 0.f);

  // 5) w-build + col norms -> X0 (f32+bf16) + X0^T
  wbuild_kernel<<<16, 256, 0, stream>>>(weight, t_out, wbuf, colpart);
  colfin_kernel<<<1, 256, 0, stream>>>(colpart, cscale);
  x0_kernel<<<1024, 256, 0, stream>>>(wbuf, cscale, Xf0, Xb0);
  transpose_kernel<<<dim3(16, 16), 256, 0, stream>>>(Xb0, XbT0, 1024, 1024);

  // 6) A0 = X0^T X0 (f32 + bf16) ; power iteration for sigma_max
  gemm_bt_kernel<64, 4, 2><<<dim3(16, 16), 512, 0, stream>>>(
      XbT0, XbT0, nullptr, nullptr, nullptr, nullptr, Af, Ab, nullptr,
      1024, 1024, 0, 0.f, 0.f, 0.f);
  pinit_kernel<<<4, 256, 0, stream>>>(vpow, norms);
  matvec_kernel<<<64, 256, 0, stream>>>(Af, vpow, vpow + 1024, norms + 0);
  matvec_kernel<<<64, 256, 0, stream>>>(Af, vpow + 1024, vpow + 2048, norms + 1);
  matvec_kernel<<<64, 256, 0, stream>>>(Af, vpow + 2048, vpow + 3072, norms + 2);
  coefq_kernel<<<1, 1, 0, stream>>>(norms, dcoef);

  const float QA = 3.4445f, QB = -4.7750f, QC = 2.0315f;
  float* Xf[2] = {Xf0, Xf1};
  unsigned short* Xb[2] = {Xb0, Xb1};
  unsigned short* XbT[2] = {XbT0, XbT1};
  int cur = 0;

  // quintic 1 (scaled via device coeffs): B = dc0*I + dc1*A0 + dc2*A0^2 ; X <- X0@B
  gemm_bt_kernel<64, 4, 2><<<dim3(16, 16), 512, 0, stream>>>(
      Ab, Ab, Af, nullptr, nullptr, dcoef, nullptr, Rb, nullptr,
      1024, 1024, 2, 0.f, 0.f, 0.f);
  gemm_bt_kernel<64, 4, 2><<<dim3(16, 16), 512, 0, stream>>>(
      Xb[cur], Rb, nullptr, nullptr, nullptr, nullptr,
      Xf[cur ^ 1], Xb[cur ^ 1], XbT[cur ^ 1], 1024, 1024, 0, 0.f, 0.f, 0.f);
  cur ^= 1;

  // quintic 2,3: A = X^T X ; B = QA*I + QB*A + QC*A^2 ; X <- X@B
  for (int q = 0; q < 2; q++) {
    gemm_bt_kernel<64, 4, 2><<<dim3(16, 16), 512, 0, stream>>>(
        XbT[cur], XbT[cur], nullptr, nullptr, nullptr, nullptr, Af, Ab, nullptr,
        1024, 1024, 0, 0.f, 0.f, 0.f);
    gemm_bt_kernel<64, 4, 2><<<dim3(16, 16), 512, 0, stream>>>(
        Ab, Ab, Af, nullptr, nullptr, nullptr, nullptr, Rb, nullptr,
        1024, 1024, 1, QA, QB, QC);
    gemm_bt_kernel<64, 4, 2><<<dim3(16, 16), 512, 0, stream>>>(
        Xb[cur], Rb, nullptr, nullptr, nullptr, nullptr,
        Xf[cur ^ 1], Xb[cur ^ 1], XbT[cur ^ 1], 1024, 1024, 0, 0.f, 0.f, 0.f);
    cur ^= 1;
  }

  // cubic 1..3: R = 0.5*(I - X^T X) ; X <- X + X@R
  for (int t = 0; t < 3; t++) {
    gemm_bt_kernel<64, 4, 2><<<dim3(16, 16), 512, 0, stream>>>(
        XbT[cur], XbT[cur], nullptr, nullptr, nullptr, nullptr, nullptr, Rb,
        nullptr, 1024, 1024, 1, 0.5f, 0.f, -0.5f);
    bool last = (t == 2);
    gemm_bt_kernel<64, 4, 2><<<dim3(16, 16), 512, 0, stream>>>(
        Xb[cur], Rb, Xf[cur], nullptr, nullptr, nullptr,
        last ? w_out : Xf[cur ^ 1],
        last ? (unsigned short*)nullptr : Xb[cur ^ 1],
        last ? (unsigned short*)nullptr : XbT[cur ^ 1],
        1024, 1024, 0, 0.f, 0.f, 0.f);
    cur ^= 1;
  }
}

// Round 2
// 413.668 us; speedup vs baseline: 1.3960x; 1.0119x over previous
//
#include <hip/hip_runtime.h>

// EfficientHebbian on MI355X (gfx950) — round 5.
// LN -> xn bf16 ; transpose -> xnT ; G = xnT@xnT^T symmetric-upper, split-16
// (partials in d_out y region) ; reduce mirrors lower triangle.
// trace = 0.9*tr + (1/32)(W@G) fused epilogue ; y = xn@W^T (NT)
// polar: power-iter sigma_max scale + 3 quintic (Muon) + 3 cubic NS.
// GEMM K-loop: DEPTH-buffer ring with raw s_barrier + counted s_waitcnt
// vmcnt(N) (T3/T4 recipe): prefetched global_load_lds stay in flight across
// barriers; exact tail immediates via switch. NK fixed = 16 (Kseg=1024).

typedef short short4v __attribute__((ext_vector_type(4)));
typedef short short8v __attribute__((ext_vector_type(8)));
typedef unsigned short ushort4v __attribute__((ext_vector_type(4)));
typedef unsigned short ushort8v __attribute__((ext_vector_type(8)));
typedef float f32x4 __attribute__((ext_vector_type(4)));

__device__ __forceinline__ unsigned short f2bf(float f) {
  union { float f; unsigned u; } v; v.f = f;
  unsigned r = 0x7fffu + ((v.u >> 16) & 1u);
  return (unsigned short)((v.u + r) >> 16);
}

__device__ __forceinline__ void gload_lds16(const void* g, void* l) {
  __builtin_amdgcn_global_load_lds(
      (const __attribute__((address_space(1))) void*)g,
      (__attribute__((address_space(3))) void*)l, 16, 0, 0);
}

// counted vmcnt wait; "memory" clobber = compiler fence for LDS/VMEM motion
__device__ __forceinline__ void waitvm(int n) {
  switch (n) {
    case 0: asm volatile("s_waitcnt vmcnt(0)" ::: "memory"); break;
    case 2: asm volatile("s_waitcnt vmcnt(2)" ::: "memory"); break;
    case 4: asm volatile("s_waitcnt vmcnt(4)" ::: "memory"); break;
    case 6: asm volatile("s_waitcnt vmcnt(6)" ::: "memory"); break;
    case 8: asm volatile("s_waitcnt vmcnt(8)" ::: "memory"); break;
    default: asm volatile("s_waitcnt vmcnt(0)" ::: "memory"); break;
  }
}

// ---------------- LayerNorm: x[row][1024] f32 -> xn bf16 ----------------
__global__ void __launch_bounds__(256) ln_kernel(
    const float* __restrict__ x, const float* __restrict__ gamma,
    const float* __restrict__ beta, unsigned short* __restrict__ xn) {
  __shared__ float sb[4];
  const int row = blockIdx.x;
  const int t = threadIdx.x;
  const float* xr = x + (size_t)row * 1024;
  f32x4 v = *(const f32x4*)(xr + t * 4);
  float s = v[0] + v[1] + v[2] + v[3];
  for (int m = 32; m; m >>= 1) s += __shfl_xor(s, m);
  if ((t & 63) == 0) sb[t >> 6] = s;
  __syncthreads();
  float mu = (sb[0] + sb[1] + sb[2] + sb[3]) * (1.0f / 1024.0f);
  __syncthreads();
  f32x4 d; float q = 0.f;
  for (int i = 0; i < 4; i++) { d[i] = v[i] - mu; q += d[i] * d[i]; }
  for (int m = 32; m; m >>= 1) q += __shfl_xor(q, m);
  if ((t & 63) == 0) sb[t >> 6] = q;
  __syncthreads();
  float var = (sb[0] + sb[1] + sb[2] + sb[3]) * (1.0f / 1024.0f);
  float rs = rsqrtf(var + 1e-5f);
  f32x4 g4 = *(const f32x4*)(gamma + t * 4);
  f32x4 b4 = *(const f32x4*)(beta + t * 4);
  ushort4v o;
  for (int i = 0; i < 4; i++) o[i] = f2bf(d[i] * rs * g4[i] + b4[i]);
  *(ushort4v*)(xn + (size_t)row * 1024 + t * 4) = o;
}

// ---------------- f32 -> bf16 convert ----------------
__global__ void __launch_bounds__(256) cvt_kernel(
    const float* __restrict__ in, unsigned short* __restrict__ out) {
  size_t e = ((size_t)blockIdx.x * 256 + threadIdx.x) * 4;
  f32x4 v = *(const f32x4*)(in + e);
  ushort4v o;
  for (int k = 0; k < 4; k++) o[k] = f2bf(v[k]);
  *(ushort4v*)(out + e) = o;
}

// ---------------- bf16 transpose: out[c][r] = in[r][c], 64x64 tiles ----------
__global__ void __launch_bounds__(256) transpose_kernel(
    const unsigned short* __restrict__ in, unsigned short* __restrict__ out,
    int R, int C) {
  __shared__ unsigned short tb[64][65];
  const int t = threadIdx.x;
  const int r0 = blockIdx.x * 64, c0 = blockIdx.y * 64;
#pragma unroll
  for (int p = 0; p < 2; p++) {
    int lr = p * 32 + (t >> 3);
    int lc = (t & 7) * 8;
    ushort8v v = *(const ushort8v*)(in + (size_t)(r0 + lr) * C + c0 + lc);
#pragma unroll
    for (int d = 0; d < 8; d++) tb[lr][lc + d] = v[d];
  }
  __syncthreads();
#pragma unroll
  for (int p = 0; p < 2; p++) {
    int orr = p * 32 + (t >> 3);
    int oc = (t & 7) * 8;
    ushort8v w;
#pragma unroll
    for (int d = 0; d < 8; d++) w[d] = tb[oc + d][orr];
    *(ushort8v*)(out + (size_t)(c0 + orr) * R + r0 + oc) = w;
  }
}

// ---------------- NT GEMM: C[M][N] = A[M][K] @ B[N][K]^T ----------------
// BM x BM tile, BK=64, NK=16 K-steps (Kseg must be 1024), WM x WN waves.
// XOR-swizzled LDS via pre-swizzled global src. DEPTH-buffer ring pipeline:
//   prologue: issue stages 0..DEPTH-2
//   step t:   waitvm(min(DEPTH-2,15-t)*L) ; s_barrier ;
//             issue stage(t+DEPTH-1) [overwrites buf read at t-1, safe
//             because barrier proves all waves consumed it] ;
//             ds_read tile t ; MFMA
// modes: 0: v=acc (+addF if set)
//        1: v = c0*(r==c) + c1*addF + c2*acc        (immediate coeffs)
//        2: v = dcoef[0]*(r==c) + dcoef[1]*addF + dcoef[2]*acc
//        3: v = 0.9*addF + (1/32)*(acc + addF2*dvec[c])   (trace epilogue)
//        5: symmetric-upper partial: blockIdx.x = triangle tile index (i<=j),
//           blockIdx.y = z-seg; outF += z<<20
// outBT (if set, BM=64 only): writes bf16 transposed tile via LDS.
template <int BM, int WM, int WN, int DEPTH>
__global__ void __launch_bounds__(WM * WN * 64, BM == 64 ? 4 : 2) gemm_bt_kernel(
    const unsigned short* __restrict__ A, const unsigned short* __restrict__ B,
    const float* __restrict__ addF, const float* __restrict__ addF2,
    const float* __restrict__ dvec, const float* __restrict__ dcoef,
    float* __restrict__ outF, unsigned short* __restrict__ outB,
    unsigned short* __restrict__ outBT,
    int ldk, int Kseg, int mode, float c0, float c1, float c2) {
  constexpr int WAVES = WM * WN;
  constexpr int NT = WAVES * 64;
  constexpr int FMm = BM / (16 * WM);
  constexpr int FMn = BM / (16 * WN);
  constexpr int CPW = BM / (8 * WAVES);  // 1KB chunks per wave per operand
  constexpr int L = 2 * CPW;             // vmem loads per wave per stage
  constexpr int BUFS = 2 * BM * 64;      // shorts per buffer (A then B)
  constexpr int NK = 16;                 // Kseg == 1024 always
  __shared__ __align__(16) unsigned short lds[DEPTH * BUFS];
  const int tid = threadIdx.x, lane = tid & 63, wv = tid >> 6;
  const int wm = wv / WN, wn = wv % WN;

  int m0, n0, kb = 0, zseg = 0;
  if (mode == 5) {
    const int ntile = 1024 / BM;
    int tt = blockIdx.x, ti = 0;
    while (tt >= ntile - ti) { tt -= ntile - ti; ++ti; }
    m0 = ti * BM; n0 = (ti + tt) * BM;
    zseg = blockIdx.y; kb = zseg * Kseg;
  } else {
    m0 = blockIdx.x * BM; n0 = blockIdx.y * BM;
  }

  const int srow = lane >> 3;
  const int skoff = 8 * ((lane & 7) ^ srow);  // pre-swizzled global k-offset

  f32x4 acc[FMm][FMn];
  for (int a = 0; a < FMm; a++)
    for (int b = 0; b < FMn; b++) acc[a][b] = (f32x4){0.f, 0.f, 0.f, 0.f};

  auto stage = [&](int buf, int kk) {
#pragma unroll
    for (int ci = 0; ci < CPW; ci++) {
      int ch = wv * CPW + ci;
      const unsigned short* ga = A + (size_t)(m0 + 8 * ch + srow) * ldk + kk + skoff;
      const unsigned short* gb = B + (size_t)(n0 + 8 * ch + srow) * ldk + kk + skoff;
      char* lb = (char*)(lds + buf * BUFS);
      gload_lds16(ga, lb + ch * 1024);
      gload_lds16(gb, lb + BM * 128 + ch * 1024);
    }
  };

  // prologue: DEPTH-1 stages in flight
#pragma unroll
  for (int d = 0; d < DEPTH - 1; ++d) stage(d, kb + (d << 6));

  for (int t = 0; t < NK; ++t) {
    int ahead = NK - 1 - t;
    if (ahead > DEPTH - 2) ahead = DEPTH - 2;
    waitvm(ahead * L);                     // tile t complete; rest in flight
    __builtin_amdgcn_s_barrier();
    if (t + DEPTH - 1 < NK) stage((t + DEPTH - 1) % DEPTH, kb + ((t + DEPTH - 1) << 6));

    const unsigned short* As = lds + (t % DEPTH) * BUFS;
    const unsigned short* Bs = As + BM * 64;
    const int g = lane >> 4;
#pragma unroll
    for (int ks = 0; ks < 2; ks++) {
      short8v af[FMm], bfr[FMn];
#pragma unroll
      for (int fm = 0; fm < FMm; fm++) {
        int row = wm * (BM / WM) + fm * 16 + (lane & 15);
        int swz = (row & 7) << 4;
        const char* rp = (const char*)As + row * 128;
        int o = ks * 64 + g * 8;
        short4v lo = *(const short4v*)(rp + (o ^ swz));
        short4v hi = *(const short4v*)(rp + ((o + 32) ^ swz));
        af[fm] = __builtin_shufflevector(lo, hi, 0, 1, 2, 3, 4, 5, 6, 7);
      }
#pragma unroll
      for (int fn = 0; fn < FMn; fn++) {
        int row = wn * (BM / WN) + fn * 16 + (lane & 15);
        int swz = (row & 7) << 4;
        const char* rp = (const char*)Bs + row * 128;
        int o = ks * 64 + g * 8;
        short4v lo = *(const short4v*)(rp + (o ^ swz));
        short4v hi = *(const short4v*)(rp + ((o + 32) ^ swz));
        bfr[fn] = __builtin_shufflevector(lo, hi, 0, 1, 2, 3, 4, 5, 6, 7);
      }
#pragma unroll
      for (int fm = 0; fm < FMm; fm++)
#pragma unroll
        for (int fn = 0; fn < FMn; fn++)
          acc[fm][fn] = __builtin_amdgcn_mfma_f32_16x16x32_bf16(
              af[fm], bfr[fn], acc[fm][fn], 0, 0, 0);
    }
  }

  float* of = outF;
  if (mode == 5 && of) of += ((size_t)zseg << 20);
  float dc0 = 0.f, dc1 = 0.f, dc2 = 0.f;
  if (mode == 2) { dc0 = dcoef[0]; dc1 = dcoef[1]; dc2 = dcoef[2]; }

#pragma unroll
  for (int fm = 0; fm < FMm; fm++) {
    int r0 = m0 + wm * (BM / WM) + fm * 16 + (lane >> 4) * 4;
#pragma unroll
    for (int fn = 0; fn < FMn; fn++) {
      int c = n0 + wn * (BM / WN) + fn * 16 + (lane & 15);
#pragma unroll
      for (int j = 0; j < 4; j++) {
        int r = r0 + j;
        size_t off = (size_t)r * 1024 + c;
        float v = acc[fm][fn][j];
        if (mode == 0) {
          if (addF) v += addF[off];
        } else if (mode == 1) {
          v = c0 * (r == c ? 1.f : 0.f) + (addF ? c1 * addF[off] : 0.f) + c2 * v;
        } else if (mode == 2) {
          v = dc0 * (r == c ? 1.f : 0.f) + dc1 * addF[off] + dc2 * v;
        } else if (mode == 3) {
          v = 0.9f * addF[off] + 0.03125f * (v + addF2[off] * dvec[c]);
        }
        if (of) of[off] = v;
        if (outB) outB[off] = f2bf(v);
        acc[fm][fn][j] = v;
      }
    }
  }

  // optional transposed bf16 output (used by BM=64 NS X-updates only)
  if (outBT) {
    constexpr int LDT = BM + 1;
    __syncthreads();
#pragma unroll
    for (int fm = 0; fm < FMm; fm++) {
      int lr0 = wm * (BM / WM) + fm * 16 + (lane >> 4) * 4;
#pragma unroll
      for (int fn = 0; fn < FMn; fn++) {
        int lc = wn * (BM / WN) + fn * 16 + (lane & 15);
#pragma unroll
        for (int j = 0; j < 4; j++)
          lds[(lr0 + j) * LDT + lc] = f2bf(acc[fm][fn][j]);
      }
    }
    __syncthreads();
    for (int e = tid * 8; e < BM * BM; e += NT * 8) {
      int orr = e / BM;          // output row = col of tile
      int oc = e % BM;           // output col base = row of tile
      ushort8v w;
#pragma unroll
      for (int d = 0; d < 8; d++) w[d] = lds[(oc + d) * LDT + orr];
      *(ushort8v*)(outBT + (size_t)(n0 + orr) * 1024 + m0 + oc) = w;
    }
  }
}

// ---- reduce G: sum 16 partials over upper 128^2 tiles -> Gb bf16, mirror
// lower triangle, diag zeroed + gdiag. grid: dim3(16 subblocks, 36 tiles).
__global__ void __launch_bounds__(256) reduce_g_kernel(
    const float* __restrict__ P, unsigned short* __restrict__ Gb,
    float* __restrict__ gdiag) {
  int tt = blockIdx.y, ti = 0;
  while (tt >= 8 - ti) { tt -= 8 - ti; ++ti; }
  const int tj = ti + tt;
  const int eloc = (blockIdx.x * 256 + threadIdx.x) * 4;
  const int lr = eloc >> 7, lc = eloc & 127;
  const int r = ti * 128 + lr, c0 = tj * 128 + lc;
  const size_t off = (size_t)r * 1024 + c0;
  f32x4 s = *(const f32x4*)(P + off);
#pragma unroll
  for (int z = 1; z < 16; z++)
    s += *(const f32x4*)(P + ((size_t)z << 20) + off);
  ushort4v o;
#pragma unroll
  for (int q = 0; q < 4; q++) {
    int c = c0 + q;
    unsigned short b = f2bf(s[q]);
    if (ti == tj && c == r) { gdiag[r] = s[q]; o[q] = 0; }
    else o[q] = b;
    if (ti != tj) Gb[(size_t)c * 1024 + r] = b;  // mirror into lower triangle
  }
  *(ushort4v*)(Gb + off) = o;
}

// ---------------- w = weight + 0.01*clip(trace,-1,1); per-column sumsq -------
__global__ void __launch_bounds__(256) wbuild_kernel(
    const float* __restrict__ weight, const float* __restrict__ tout,
    float* __restrict__ w, float* __restrict__ colpart) {
  int t = threadIdx.x, blk = blockIdx.x;
  float cs[4] = {0.f, 0.f, 0.f, 0.f};
  for (int r = 0; r < 64; r++) {
    size_t row = (size_t)blk * 64 + r;
    for (int cc = 0; cc < 4; cc++) {
      size_t idx = row * 1024 + cc * 256 + t;
      float u = tout[idx];
      u = fminf(fmaxf(u, -1.f), 1.f);
      float wv = weight[idx] + 0.01f * u;
      w[idx] = wv;
      cs[cc] += wv * wv;
    }
  }
  for (int cc = 0; cc < 4; cc++) colpart[blk * 1024 + cc * 256 + t] = cs[cc];
}

// ---------------- cscale[j] = 1/max(colnorm_j,1e-3) (no fro) ----------------
__global__ void __launch_bounds__(256) colfin_kernel(
    const float* __restrict__ colpart, float* __restrict__ cscale) {
  int t = threadIdx.x;
  for (int q = 0; q < 4; q++) {
    int j = t * 4 + q;
    float s = 0.f;
    for (int b = 0; b < 16; b++) s += colpart[b * 1024 + j];
    float cn = fmaxf(sqrtf(s), 1e-3f);
    cscale[j] = 1.f / cn;
  }
}

// ---------------- X0 = w * cscale (f32 + bf16) ----------------
__global__ void __launch_bounds__(256) x0_kernel(
    const float* __restrict__ w, const float* __restrict__ cscale,
    float* __restrict__ X, unsigned short* __restrict__ Xb) {
  size_t e = ((size_t)blockIdx.x * 256 + threadIdx.x) * 4;
  int j = (int)(e & 1023);
  f32x4 wv = *(const f32x4*)(w + e);
  f32x4 cs = *(const f32x4*)(cscale + j);
  f32x4 xo; ushort4v xb;
  for (int q = 0; q < 4; q++) { xo[q] = wv[q] * cs[q]; xb[q] = f2bf(xo[q]); }
  *(f32x4*)(X + e) = xo;
  *(ushort4v*)(Xb + e) = xb;
}

// ---------------- power-iteration init: v0 = +/-1 hash; zero norms ----------
__global__ void __launch_bounds__(256) pinit_kernel(
    float* __restrict__ v0, float* __restrict__ norms) {
  int i = blockIdx.x * 256 + threadIdx.x;
  unsigned h = (unsigned)i * 2654435761u;
  v0[i] = ((h >> 16) & 1u) ? 1.f : -1.f;
  if (blockIdx.x == 0 && threadIdx.x < 4) norms[threadIdx.x] = 0.f;
}

// ---------------- matvec: vout = A vin (A f32 1024x1024); ||vout||^2 += norm --
__global__ void __launch_bounds__(256) matvec_kernel(
    const float* __restrict__ A, const float* __restrict__ vin,
    float* __restrict__ vout, float* __restrict__ normsq) {
  __shared__ float red[4];
  int t = threadIdx.x;
  int r0 = blockIdx.x * 16;
  f32x4 vv = *(const f32x4*)(vin + t * 4);
  float sq = 0.f;
  for (int r = 0; r < 16; r++) {
    f32x4 a = *(const f32x4*)(A + (size_t)(r0 + r) * 1024 + t * 4);
    float d = a[0] * vv[0] + a[1] * vv[1] + a[2] * vv[2] + a[3] * vv[3];
    for (int m = 32; m; m >>= 1) d += __shfl_xor(d, m);
    if ((t & 63) == 0) red[t >> 6] = d;
    __syncthreads();
    if (t == 0) {
      float s = red[0] + red[1] + red[2] + red[3];
      vout[r0 + r] = s;
      sq += s * s;
    }
    __syncthreads();
  }
  if (t == 0) atomicAdd(normsq, sq);
}

// ---------------- quintic-1 coefficients from power-iter norms ----------------
__global__ void coefq_kernel(const float* __restrict__ norms,
                             float* __restrict__ dcoef) {
  const float QA = 3.4445f, QB = -4.7750f, QC = 2.0315f;
  float n1 = fmaxf(norms[1], 1e-30f), n2 = fmaxf(norms[2], 1e-30f);
  float lam = sqrtf(n2 / n1);            // ~ sigma_max^2
  float s = sqrtf(fmaxf(lam, 1e-8f)) / 0.95f;
  s = fmaxf(s, 1e-3f);
  float s2 = s * s;
  dcoef[0] = QA / s;
  dcoef[1] = QB / (s * s2);
  dcoef[2] = QC / (s * s2 * s2);
}

extern "C" void kernel_launch(void* const* d_in, const int* in_sizes, int n_in,
                              void* d_out, int out_size, void* d_ws, size_t ws_size,
                              hipStream_t stream) {
  const float* x      = (const float*)d_in[0];
  const float* weight = (const float*)d_in[1];
  const float* gamma  = (const float*)d_in[2];
  const float* beta   = (const float*)d_in[3];
  const float* trace  = (const float*)d_in[4];

  float* y_out = (float*)d_out;                  // [16384,1024]
  float* w_out = y_out + (size_t)16777216;       // [1024,1024]
  float* t_out = w_out + (size_t)1048576;        // [1024,1024]

  const size_t MB = 1048576;
  char* ws = (char*)d_ws;
  unsigned short* xn   = (unsigned short*)(ws);            // 32MB
  unsigned short* xnT  = (unsigned short*)(ws + 32 * MB);  // 32MB
  float* Xf0           = (float*)(ws + 64 * MB);           // 4MB
  float* Xf1           = (float*)(ws + 68 * MB);           // 4MB
  float* wbuf          = (float*)(ws + 72 * MB);           // 4MB (reused as Af)
  float* Af            = (float*)(ws + 72 * MB);           //   alias (wbuf dead)
  unsigned short* Xb0  = (unsigned short*)(ws + 76 * MB);  // 2MB
  unsigned short* Xb1  = (unsigned short*)(ws + 78 * MB);  // 2MB
  unsigned short* XbT0 = (unsigned short*)(ws + 80 * MB);  // 2MB
  unsigned short* XbT1 = (unsigned short*)(ws + 82 * MB);  // 2MB
  unsigned short* Ab   = (unsigned short*)(ws + 84 * MB);  // 2MB
  unsigned short* Rb   = (unsigned short*)(ws + 86 * MB);  // 2MB (also quintic B)
  unsigned short* Gb   = (unsigned short*)(ws + 88 * MB);  // 2MB
  unsigned short* wb   = (unsigned short*)(ws + 90 * MB);  // 2MB
  float* colpart       = (float*)(ws + 92 * MB);           // 64KB
  float* cscale        = (float*)(ws + 92 * MB + 65536);   // 4KB
  float* gdiag         = (float*)(ws + 92 * MB + 69632);   // 4KB
  float* vpow          = (float*)(ws + 92 * MB + 73728);   // 4 x 4KB (v0..v3)
  float* norms         = (float*)(ws + 92 * MB + 90112);   // 64B
  float* dcoef         = (float*)(ws + 92 * MB + 90176);   // 64B

  // G partials live in the (not yet written) y region of d_out: 16 x 4MB = 64MB
  float* P = y_out;

  // 1) LN -> xn ; transpose -> xnT ; weight -> bf16
  ln_kernel<<<16384, 256, 0, stream>>>(x, gamma, beta, xn);
  transpose_kernel<<<dim3(256, 16), 256, 0, stream>>>(xn, xnT, 16384, 1024);
  cvt_kernel<<<1024, 256, 0, stream>>>(weight, wb);

  // 2) G = xnT @ xnT^T symmetric: upper 36 tiles, K=16384 split-16 -> P
  gemm_bt_kernel<128, 2, 4, 3><<<dim3(36, 16), 512, 0, stream>>>(
      xnT, xnT, nullptr, nullptr, nullptr, nullptr, P, nullptr, nullptr,
      16384, 1024, 5, 0.f, 0.f, 0.f);
  reduce_g_kernel<<<dim3(16, 36), 256, 0, stream>>>(P, Gb, gdiag);

  // 3) t_out = 0.9*trace + (1/32)*(W@G)  (diag of G corrected in f32)
  gemm_bt_kernel<64, 4, 2, 4><<<dim3(16, 16), 512, 0, stream>>>(
      wb, Gb, trace, weight, gdiag, nullptr, t_out, nullptr, nullptr,
      1024, 1024, 3, 0.f, 0.f, 0.f);

  // 4) y = xn @ W^T (overwrites P region)
  gemm_bt_kernel<128, 2, 4, 3><<<dim3(128, 8), 512, 0, stream>>>(
      xn, wb, nullptr, nullptr, nullptr, nullptr, y_out, nullptr, nullptr,
      1024, 1024, 0, 0.f, 0.f, 0.f);

  // 5) w-build + col norms -> X0 (f32+bf16) + X0^T
  wbuild_kernel<<<16, 256, 0, stream>>>(weight, t_out, wbuf, colpart);
  colfin_kernel<<<1, 256, 0, stream>>>(colpart, cscale);
  x0_kernel<<<1024, 256, 0, stream>>>(wbuf, cscale, Xf0, Xb0);
  transpose_kernel<<<dim3(16, 16), 256, 0, stream>>>(Xb0, XbT0, 1024, 1024);

  // 6) A0 = X0^T X0 (f32 + bf16) ; power iteration for sigma_max
  gemm_bt_kernel<64, 4, 2, 4><<<dim3(16, 16), 512, 0, stream>>>(
      XbT0, XbT0, nullptr, nullptr, nullptr, nullptr, Af, Ab, nullptr,
      1024, 1024, 0, 0.f, 0.f, 0.f);
  pinit_kernel<<<4, 256, 0, stream>>>(vpow, norms);
  matvec_kernel<<<64, 256, 0, stream>>>(Af, vpow, vpow + 1024, norms + 0);
  matvec_kernel<<<64, 256, 0, stream>>>(Af, vpow + 1024, vpow + 2048, norms + 1);
  matvec_kernel<<<64, 256, 0, stream>>>(Af, vpow + 2048, vpow + 3072, norms + 2);
  coefq_kernel<<<1, 1, 0, stream>>>(norms, dcoef);

  const float QA = 3.4445f, QB = -4.7750f, QC = 2.0315f;
  float* Xf[2] = {Xf0, Xf1};
  unsigned short* Xb[2] = {Xb0, Xb1};
  unsigned short* XbT[2] = {XbT0, XbT1};
  int cur = 0;

  // quintic 1 (scaled via device coeffs): B = dc0*I + dc1*A0 + dc2*A0^2 ; X <- X0@B
  gemm_bt_kernel<64, 4, 2, 4><<<dim3(16, 16), 512, 0, stream>>>(
      Ab, Ab, Af, nullptr, nullptr, dcoef, nullptr, Rb, nullptr,
      1024, 1024, 2, 0.f, 0.f, 0.f);
  gemm_bt_kernel<64, 4, 2, 4><<<dim3(16, 16), 512, 0, stream>>>(
      Xb[cur], Rb, nullptr, nullptr, nullptr, nullptr,
      Xf[cur ^ 1], Xb[cur ^ 1], XbT[cur ^ 1], 1024, 1024, 0, 0.f, 0.f, 0.f);
  cur ^= 1;

  // quintic 2,3: A = X^T X ; B = QA*I + QB*A + QC*A^2 ; X <- X@B
  for (int q = 0; q < 2; q++) {
    gemm_bt_kernel<64, 4, 2, 4><<<dim3(16, 16), 512, 0, stream>>>(
        XbT[cur], XbT[cur], nullptr, nullptr, nullptr, nullptr, Af, Ab, nullptr,
        1024, 1024, 0, 0.f, 0.f, 0.f);
    gemm_bt_kernel<64, 4, 2, 4><<<dim3(16, 16), 512, 0, stream>>>(
        Ab, Ab, Af, nullptr, nullptr, nullptr, nullptr, Rb, nullptr,
        1024, 1024, 1, QA, QB, QC);
    gemm_bt_kernel<64, 4, 2, 4><<<dim3(16, 16), 512, 0, stream>>>(
        Xb[cur], Rb, nullptr, nullptr, nullptr, nullptr,
        Xf[cur ^ 1], Xb[cur ^ 1], XbT[cur ^ 1], 1024, 1024, 0, 0.f, 0.f, 0.f);
    cur ^= 1;
  }

  // cubic 1..3: R = 0.5*(I - X^T X) ; X <- X + X@R
  for (int t = 0; t < 3; t++) {
    gemm_bt_kernel<64, 4, 2, 4><<<dim3(16, 16), 512, 0, stream>>>(
        XbT[cur], XbT[cur], nullptr, nullptr, nullptr, nullptr, nullptr, Rb,
        nullptr, 1024, 1024, 1, 0.5f, 0.f, -0.5f);
    bool last = (t == 2);
    gemm_bt_kernel<64, 4, 2, 4><<<dim3(16, 16), 512, 0, stream>>>(
        Xb[cur], Rb, Xf[cur], nullptr, nullptr, nullptr,
        last ? w_out : Xf[cur ^ 1],
        last ? (unsigned short*)nullptr : Xb[cur ^ 1],
        last ? (unsigned short*)nullptr : XbT[cur ^ 1],
        1024, 1024, 0, 0.f, 0.f, 0.f);
    cur ^= 1;
  }
}

// Round 3
// 376.723 us; speedup vs baseline: 1.5329x; 1.0981x over previous
//
#include <hip/hip_runtime.h>

// EfficientHebbian on MI355X (gfx950) — round 6.
// LN -> xn bf16 ; transpose -> xnT ; G = xnT@xnT^T symmetric-upper, split-16
// (partials in d_out y region) ; reduce mirrors lower triangle.
// trace = 0.9*tr + (1/32)(W@G) fused epilogue ; y = xn@W^T (NT, XCD-swizzled)
// polar: power-iter sigma_max scale + 3 quintic (Muon) + 3 cubic NS.
// GEMM K-loop: DEPTH-buffer ring, raw s_barrier + counted s_waitcnt vmcnt(N).
//  - BM=128 big GEMMs: DEPTH=2, 256 thr, 64KB LDS -> 2 blocks/CU (TLP, r4-proven)
//  - BM=64 small GEMMs: DEPTH=8, 512 thr, 128KB LDS -> 6-step lookahead
//    (grid=256=1 block/CU anyway, so deep LDS is free; latency-bound fix)

typedef short short4v __attribute__((ext_vector_type(4)));
typedef short short8v __attribute__((ext_vector_type(8)));
typedef unsigned short ushort4v __attribute__((ext_vector_type(4)));
typedef unsigned short ushort8v __attribute__((ext_vector_type(8)));
typedef float f32x4 __attribute__((ext_vector_type(4)));

__device__ __forceinline__ unsigned short f2bf(float f) {
  union { float f; unsigned u; } v; v.f = f;
  unsigned r = 0x7fffu + ((v.u >> 16) & 1u);
  return (unsigned short)((v.u + r) >> 16);
}

__device__ __forceinline__ void gload_lds16(const void* g, void* l) {
  __builtin_amdgcn_global_load_lds(
      (const __attribute__((address_space(1))) void*)g,
      (__attribute__((address_space(3))) void*)l, 16, 0, 0);
}

// counted vmcnt wait; "memory" clobber = compiler fence for LDS/VMEM motion
__device__ __forceinline__ void waitvm(int n) {
  switch (n) {
    case 0: asm volatile("s_waitcnt vmcnt(0)" ::: "memory"); break;
    case 2: asm volatile("s_waitcnt vmcnt(2)" ::: "memory"); break;
    case 4: asm volatile("s_waitcnt vmcnt(4)" ::: "memory"); break;
    case 6: asm volatile("s_waitcnt vmcnt(6)" ::: "memory"); break;
    case 8: asm volatile("s_waitcnt vmcnt(8)" ::: "memory"); break;
    case 10: asm volatile("s_waitcnt vmcnt(10)" ::: "memory"); break;
    case 12: asm volatile("s_waitcnt vmcnt(12)" ::: "memory"); break;
    default: asm volatile("s_waitcnt vmcnt(0)" ::: "memory"); break;
  }
}

// ---------------- LayerNorm: x[row][1024] f32 -> xn bf16 ----------------
__global__ void __launch_bounds__(256) ln_kernel(
    const float* __restrict__ x, const float* __restrict__ gamma,
    const float* __restrict__ beta, unsigned short* __restrict__ xn) {
  __shared__ float sb[4];
  const int row = blockIdx.x;
  const int t = threadIdx.x;
  const float* xr = x + (size_t)row * 1024;
  f32x4 v = *(const f32x4*)(xr + t * 4);
  float s = v[0] + v[1] + v[2] + v[3];
  for (int m = 32; m; m >>= 1) s += __shfl_xor(s, m);
  if ((t & 63) == 0) sb[t >> 6] = s;
  __syncthreads();
  float mu = (sb[0] + sb[1] + sb[2] + sb[3]) * (1.0f / 1024.0f);
  __syncthreads();
  f32x4 d; float q = 0.f;
  for (int i = 0; i < 4; i++) { d[i] = v[i] - mu; q += d[i] * d[i]; }
  for (int m = 32; m; m >>= 1) q += __shfl_xor(q, m);
  if ((t & 63) == 0) sb[t >> 6] = q;
  __syncthreads();
  float var = (sb[0] + sb[1] + sb[2] + sb[3]) * (1.0f / 1024.0f);
  float rs = rsqrtf(var + 1e-5f);
  f32x4 g4 = *(const f32x4*)(gamma + t * 4);
  f32x4 b4 = *(const f32x4*)(beta + t * 4);
  ushort4v o;
  for (int i = 0; i < 4; i++) o[i] = f2bf(d[i] * rs * g4[i] + b4[i]);
  *(ushort4v*)(xn + (size_t)row * 1024 + t * 4) = o;
}

// ---------------- f32 -> bf16 convert ----------------
__global__ void __launch_bounds__(256) cvt_kernel(
    const float* __restrict__ in, unsigned short* __restrict__ out) {
  size_t e = ((size_t)blockIdx.x * 256 + threadIdx.x) * 4;
  f32x4 v = *(const f32x4*)(in + e);
  ushort4v o;
  for (int k = 0; k < 4; k++) o[k] = f2bf(v[k]);
  *(ushort4v*)(out + e) = o;
}

// ---------------- bf16 transpose: out[c][r] = in[r][c], 64x64 tiles ----------
__global__ void __launch_bounds__(256) transpose_kernel(
    const unsigned short* __restrict__ in, unsigned short* __restrict__ out,
    int R, int C) {
  __shared__ unsigned short tb[64][65];
  const int t = threadIdx.x;
  const int r0 = blockIdx.x * 64, c0 = blockIdx.y * 64;
#pragma unroll
  for (int p = 0; p < 2; p++) {
    int lr = p * 32 + (t >> 3);
    int lc = (t & 7) * 8;
    ushort8v v = *(const ushort8v*)(in + (size_t)(r0 + lr) * C + c0 + lc);
#pragma unroll
    for (int d = 0; d < 8; d++) tb[lr][lc + d] = v[d];
  }
  __syncthreads();
#pragma unroll
  for (int p = 0; p < 2; p++) {
    int orr = p * 32 + (t >> 3);
    int oc = (t & 7) * 8;
    ushort8v w;
#pragma unroll
    for (int d = 0; d < 8; d++) w[d] = tb[oc + d][orr];
    *(ushort8v*)(out + (size_t)(c0 + orr) * R + r0 + oc) = w;
  }
}

// ---------------- NT GEMM: C[M][N] = A[M][K] @ B[N][K]^T ----------------
// BM x BM tile, BK=64, NK=16 K-steps (Kseg must be 1024), WM x WN waves.
// XOR-swizzled LDS via pre-swizzled global src. DEPTH-buffer ring pipeline:
//   prologue: issue stages 0..DEPTH-2
//   step t:   waitvm(min(DEPTH-2,15-t)*L) ; s_barrier ;
//             issue stage(t+DEPTH-1) [buf read at t-1; barrier proves all
//             waves consumed it] ; ds_read tile t ; MFMA
// modes: 0: v=acc (+addF if set)
//        1: v = c0*(r==c) + c1*addF + c2*acc        (immediate coeffs)
//        2: v = dcoef[0]*(r==c) + dcoef[1]*addF + dcoef[2]*acc
//        3: v = 0.9*addF + (1/32)*(acc + addF2*dvec[c])   (trace epilogue)
//        5: symmetric-upper partial: blockIdx.x = triangle tile index (i<=j),
//           blockIdx.y = z-seg; outF += z<<20
//        6: as mode 0 but flat 1D grid with XCD swizzle (M=128,N=8 tiles):
//           c=l&7 (XCD), s=l>>3: m-tile = c*16+(s>>3), n-tile = s&7
// outBT (if set, BM=64 only): writes bf16 transposed tile via LDS.
template <int BM, int WM, int WN, int DEPTH>
__global__ void __launch_bounds__(WM * WN * 64, 2) gemm_bt_kernel(
    const unsigned short* __restrict__ A, const unsigned short* __restrict__ B,
    const float* __restrict__ addF, const float* __restrict__ addF2,
    const float* __restrict__ dvec, const float* __restrict__ dcoef,
    float* __restrict__ outF, unsigned short* __restrict__ outB,
    unsigned short* __restrict__ outBT,
    int ldk, int Kseg, int mode, float c0, float c1, float c2) {
  constexpr int WAVES = WM * WN;
  constexpr int NT = WAVES * 64;
  constexpr int FMm = BM / (16 * WM);
  constexpr int FMn = BM / (16 * WN);
  constexpr int CPW = BM / (8 * WAVES);  // 1KB chunks per wave per operand
  constexpr int L = 2 * CPW;             // vmem loads per wave per stage
  constexpr int BUFS = 2 * BM * 64;      // shorts per buffer (A then B)
  constexpr int NK = 16;                 // Kseg == 1024 always
  __shared__ __align__(16) unsigned short lds[DEPTH * BUFS];
  const int tid = threadIdx.x, lane = tid & 63, wv = tid >> 6;
  const int wm = wv / WN, wn = wv % WN;

  int m0, n0, kb = 0, zseg = 0;
  if (mode == 5) {
    const int ntile = 1024 / BM;
    int tt = blockIdx.x, ti = 0;
    while (tt >= ntile - ti) { tt -= ntile - ti; ++ti; }
    m0 = ti * BM; n0 = (ti + tt) * BM;
    zseg = blockIdx.y; kb = zseg * Kseg;
  } else if (mode == 6) {
    int l = blockIdx.x;
    int c = l & 7, s = l >> 3;
    m0 = (c * 16 + (s >> 3)) * BM;
    n0 = (s & 7) * BM;
  } else {
    m0 = blockIdx.x * BM; n0 = blockIdx.y * BM;
  }

  const int srow = lane >> 3;
  const int skoff = 8 * ((lane & 7) ^ srow);  // pre-swizzled global k-offset

  f32x4 acc[FMm][FMn];
  for (int a = 0; a < FMm; a++)
    for (int b = 0; b < FMn; b++) acc[a][b] = (f32x4){0.f, 0.f, 0.f, 0.f};

  auto stage = [&](int buf, int kk) {
#pragma unroll
    for (int ci = 0; ci < CPW; ci++) {
      int ch = wv * CPW + ci;
      const unsigned short* ga = A + (size_t)(m0 + 8 * ch + srow) * ldk + kk + skoff;
      const unsigned short* gb = B + (size_t)(n0 + 8 * ch + srow) * ldk + kk + skoff;
      char* lb = (char*)(lds + buf * BUFS);
      gload_lds16(ga, lb + ch * 1024);
      gload_lds16(gb, lb + BM * 128 + ch * 1024);
    }
  };

  // prologue: DEPTH-1 stages in flight
#pragma unroll
  for (int d = 0; d < DEPTH - 1; ++d) stage(d, kb + (d << 6));

#pragma unroll
  for (int t = 0; t < NK; ++t) {
    int ahead = NK - 1 - t;
    if (ahead > DEPTH - 2) ahead = DEPTH - 2;
    waitvm(ahead * L);                     // tile t complete; rest in flight
    __builtin_amdgcn_s_barrier();
    if (t + DEPTH - 1 < NK) stage((t + DEPTH - 1) % DEPTH, kb + ((t + DEPTH - 1) << 6));

    const unsigned short* As = lds + (t % DEPTH) * BUFS;
    const unsigned short* Bs = As + BM * 64;
    const int g = lane >> 4;
#pragma unroll
    for (int ks = 0; ks < 2; ks++) {
      short8v af[FMm], bfr[FMn];
#pragma unroll
      for (int fm = 0; fm < FMm; fm++) {
        int row = wm * (BM / WM) + fm * 16 + (lane & 15);
        int swz = (row & 7) << 4;
        const char* rp = (const char*)As + row * 128;
        int o = ks * 64 + g * 8;
        short4v lo = *(const short4v*)(rp + (o ^ swz));
        short4v hi = *(const short4v*)(rp + ((o + 32) ^ swz));
        af[fm] = __builtin_shufflevector(lo, hi, 0, 1, 2, 3, 4, 5, 6, 7);
      }
#pragma unroll
      for (int fn = 0; fn < FMn; fn++) {
        int row = wn * (BM / WN) + fn * 16 + (lane & 15);
        int swz = (row & 7) << 4;
        const char* rp = (const char*)Bs + row * 128;
        int o = ks * 64 + g * 8;
        short4v lo = *(const short4v*)(rp + (o ^ swz));
        short4v hi = *(const short4v*)(rp + ((o + 32) ^ swz));
        bfr[fn] = __builtin_shufflevector(lo, hi, 0, 1, 2, 3, 4, 5, 6, 7);
      }
#pragma unroll
      for (int fm = 0; fm < FMm; fm++)
#pragma unroll
        for (int fn = 0; fn < FMn; fn++)
          acc[fm][fn] = __builtin_amdgcn_mfma_f32_16x16x32_bf16(
              af[fm], bfr[fn], acc[fm][fn], 0, 0, 0);
    }
  }

  float* of = outF;
  if (mode == 5 && of) of += ((size_t)zseg << 20);
  float dc0 = 0.f, dc1 = 0.f, dc2 = 0.f;
  if (mode == 2) { dc0 = dcoef[0]; dc1 = dcoef[1]; dc2 = dcoef[2]; }

#pragma unroll
  for (int fm = 0; fm < FMm; fm++) {
    int r0 = m0 + wm * (BM / WM) + fm * 16 + (lane >> 4) * 4;
#pragma unroll
    for (int fn = 0; fn < FMn; fn++) {
      int c = n0 + wn * (BM / WN) + fn * 16 + (lane & 15);
#pragma unroll
      for (int j = 0; j < 4; j++) {
        int r = r0 + j;
        size_t off = (size_t)r * 1024 + c;
        float v = acc[fm][fn][j];
        if (mode == 0 || mode == 6) {
          if (addF) v += addF[off];
        } else if (mode == 1) {
          v = c0 * (r == c ? 1.f : 0.f) + (addF ? c1 * addF[off] : 0.f) + c2 * v;
        } else if (mode == 2) {
          v = dc0 * (r == c ? 1.f : 0.f) + dc1 * addF[off] + dc2 * v;
        } else if (mode == 3) {
          v = 0.9f * addF[off] + 0.03125f * (v + addF2[off] * dvec[c]);
        }
        if (of) of[off] = v;
        if (outB) outB[off] = f2bf(v);
        acc[fm][fn][j] = v;
      }
    }
  }

  // optional transposed bf16 output (used by BM=64 NS X-updates only)
  if (outBT) {
    constexpr int LDT = BM + 1;
    __syncthreads();
#pragma unroll
    for (int fm = 0; fm < FMm; fm++) {
      int lr0 = wm * (BM / WM) + fm * 16 + (lane >> 4) * 4;
#pragma unroll
      for (int fn = 0; fn < FMn; fn++) {
        int lc = wn * (BM / WN) + fn * 16 + (lane & 15);
#pragma unroll
        for (int j = 0; j < 4; j++)
          lds[(lr0 + j) * LDT + lc] = f2bf(acc[fm][fn][j]);
      }
    }
    __syncthreads();
    for (int e = tid * 8; e < BM * BM; e += NT * 8) {
      int orr = e / BM;          // output row = col of tile
      int oc = e % BM;           // output col base = row of tile
      ushort8v w;
#pragma unroll
      for (int d = 0; d < 8; d++) w[d] = lds[(oc + d) * LDT + orr];
      *(ushort8v*)(outBT + (size_t)(n0 + orr) * 1024 + m0 + oc) = w;
    }
  }
}

// ---- reduce G: sum 16 partials over upper 128^2 tiles -> Gb bf16, mirror
// lower triangle, diag zeroed + gdiag. grid: dim3(16 subblocks, 36 tiles).
__global__ void __launch_bounds__(256) reduce_g_kernel(
    const float* __restrict__ P, unsigned short* __restrict__ Gb,
    float* __restrict__ gdiag) {
  int tt = blockIdx.y, ti = 0;
  while (tt >= 8 - ti) { tt -= 8 - ti; ++ti; }
  const int tj = ti + tt;
  const int eloc = (blockIdx.x * 256 + threadIdx.x) * 4;
  const int lr = eloc >> 7, lc = eloc & 127;
  const int r = ti * 128 + lr, c0 = tj * 128 + lc;
  const size_t off = (size_t)r * 1024 + c0;
  f32x4 s = *(const f32x4*)(P + off);
#pragma unroll
  for (int z = 1; z < 16; z++)
    s += *(const f32x4*)(P + ((size_t)z << 20) + off);
  ushort4v o;
#pragma unroll
  for (int q = 0; q < 4; q++) {
    int c = c0 + q;
    unsigned short b = f2bf(s[q]);
    if (ti == tj && c == r) { gdiag[r] = s[q]; o[q] = 0; }
    else o[q] = b;
    if (ti != tj) Gb[(size_t)c * 1024 + r] = b;  // mirror into lower triangle
  }
  *(ushort4v*)(Gb + off) = o;
}

// ---------------- w = weight + 0.01*clip(trace,-1,1); per-column sumsq -------
__global__ void __launch_bounds__(256) wbuild_kernel(
    const float* __restrict__ weight, const float* __restrict__ tout,
    float* __restrict__ w, float* __restrict__ colpart) {
  int t = threadIdx.x, blk = blockIdx.x;
  float cs[4] = {0.f, 0.f, 0.f, 0.f};
  for (int r = 0; r < 64; r++) {
    size_t row = (size_t)blk * 64 + r;
    for (int cc = 0; cc < 4; cc++) {
      size_t idx = row * 1024 + cc * 256 + t;
      float u = tout[idx];
      u = fminf(fmaxf(u, -1.f), 1.f);
      float wv = weight[idx] + 0.01f * u;
      w[idx] = wv;
      cs[cc] += wv * wv;
    }
  }
  for (int cc = 0; cc < 4; cc++) colpart[blk * 1024 + cc * 256 + t] = cs[cc];
}

// ---------------- cscale[j] = 1/max(colnorm_j,1e-3) (no fro) ----------------
__global__ void __launch_bounds__(256) colfin_kernel(
    const float* __restrict__ colpart, float* __restrict__ cscale) {
  int t = threadIdx.x;
  for (int q = 0; q < 4; q++) {
    int j = t * 4 + q;
    float s = 0.f;
    for (int b = 0; b < 16; b++) s += colpart[b * 1024 + j];
    float cn = fmaxf(sqrtf(s), 1e-3f);
    cscale[j] = 1.f / cn;
  }
}

// ---------------- X0 = w * cscale (f32 + bf16) ----------------
__global__ void __launch_bounds__(256) x0_kernel(
    const float* __restrict__ w, const float* __restrict__ cscale,
    float* __restrict__ X, unsigned short* __restrict__ Xb) {
  size_t e = ((size_t)blockIdx.x * 256 + threadIdx.x) * 4;
  int j = (int)(e & 1023);
  f32x4 wv = *(const f32x4*)(w + e);
  f32x4 cs = *(const f32x4*)(cscale + j);
  f32x4 xo; ushort4v xb;
  for (int q = 0; q < 4; q++) { xo[q] = wv[q] * cs[q]; xb[q] = f2bf(xo[q]); }
  *(f32x4*)(X + e) = xo;
  *(ushort4v*)(Xb + e) = xb;
}

// ---------------- power-iteration init: v0 = +/-1 hash; zero norms ----------
__global__ void __launch_bounds__(256) pinit_kernel(
    float* __restrict__ v0, float* __restrict__ norms) {
  int i = blockIdx.x * 256 + threadIdx.x;
  unsigned h = (unsigned)i * 2654435761u;
  v0[i] = ((h >> 16) & 1u) ? 1.f : -1.f;
  if (blockIdx.x == 0 && threadIdx.x < 4) norms[threadIdx.x] = 0.f;
}

// ---------------- matvec: vout = A vin (A f32 1024x1024); ||vout||^2 += norm --
__global__ void __launch_bounds__(256) matvec_kernel(
    const float* __restrict__ A, const float* __restrict__ vin,
    float* __restrict__ vout, float* __restrict__ normsq) {
  __shared__ float red[4];
  int t = threadIdx.x;
  int r0 = blockIdx.x * 16;
  f32x4 vv = *(const f32x4*)(vin + t * 4);
  float sq = 0.f;
  for (int r = 0; r < 16; r++) {
    f32x4 a = *(const f32x4*)(A + (size_t)(r0 + r) * 1024 + t * 4);
    float d = a[0] * vv[0] + a[1] * vv[1] + a[2] * vv[2] + a[3] * vv[3];
    for (int m = 32; m; m >>= 1) d += __shfl_xor(d, m);
    if ((t & 63) == 0) red[t >> 6] = d;
    __syncthreads();
    if (t == 0) {
      float s = red[0] + red[1] + red[2] + red[3];
      vout[r0 + r] = s;
      sq += s * s;
    }
    __syncthreads();
  }
  if (t == 0) atomicAdd(normsq, sq);
}

// ---------------- quintic-1 coefficients from power-iter norms ----------------
__global__ void coefq_kernel(const float* __restrict__ norms,
                             float* __restrict__ dcoef) {
  const float QA = 3.4445f, QB = -4.7750f, QC = 2.0315f;
  float n1 = fmaxf(norms[1], 1e-30f), n2 = fmaxf(norms[2], 1e-30f);
  float lam = sqrtf(n2 / n1);            // ~ sigma_max^2
  float s = sqrtf(fmaxf(lam, 1e-8f)) / 0.95f;
  s = fmaxf(s, 1e-3f);
  float s2 = s * s;
  dcoef[0] = QA / s;
  dcoef[1] = QB / (s * s2);
  dcoef[2] = QC / (s * s2 * s2);
}

extern "C" void kernel_launch(void* const* d_in, const int* in_sizes, int n_in,
                              void* d_out, int out_size, void* d_ws, size_t ws_size,
                              hipStream_t stream) {
  const float* x      = (const float*)d_in[0];
  const float* weight = (const float*)d_in[1];
  const float* gamma  = (const float*)d_in[2];
  const float* beta   = (const float*)d_in[3];
  const float* trace  = (const float*)d_in[4];

  float* y_out = (float*)d_out;                  // [16384,1024]
  float* w_out = y_out + (size_t)16777216;       // [1024,1024]
  float* t_out = w_out + (size_t)1048576;        // [1024,1024]

  const size_t MB = 1048576;
  char* ws = (char*)d_ws;
  unsigned short* xn   = (unsigned short*)(ws);            // 32MB
  unsigned short* xnT  = (unsigned short*)(ws + 32 * MB);  // 32MB
  float* Xf0           = (float*)(ws + 64 * MB);           // 4MB
  float* Xf1           = (float*)(ws + 68 * MB);           // 4MB
  float* wbuf          = (float*)(ws + 72 * MB);           // 4MB (reused as Af)
  float* Af            = (float*)(ws + 72 * MB);           //   alias (wbuf dead)
  unsigned short* Xb0  = (unsigned short*)(ws + 76 * MB);  // 2MB
  unsigned short* Xb1  = (unsigned short*)(ws + 78 * MB);  // 2MB
  unsigned short* XbT0 = (unsigned short*)(ws + 80 * MB);  // 2MB
  unsigned short* XbT1 = (unsigned short*)(ws + 82 * MB);  // 2MB
  unsigned short* Ab   = (unsigned short*)(ws + 84 * MB);  // 2MB
  unsigned short* Rb   = (unsigned short*)(ws + 86 * MB);  // 2MB (also quintic B)
  unsigned short* Gb   = (unsigned short*)(ws + 88 * MB);  // 2MB
  unsigned short* wb   = (unsigned short*)(ws + 90 * MB);  // 2MB
  float* colpart       = (float*)(ws + 92 * MB);           // 64KB
  float* cscale        = (float*)(ws + 92 * MB + 65536);   // 4KB
  float* gdiag         = (float*)(ws + 92 * MB + 69632);   // 4KB
  float* vpow          = (float*)(ws + 92 * MB + 73728);   // 4 x 4KB (v0..v3)
  float* norms         = (float*)(ws + 92 * MB + 90112);   // 64B
  float* dcoef         = (float*)(ws + 92 * MB + 90176);   // 64B

  // G partials live in the (not yet written) y region of d_out: 16 x 4MB = 64MB
  float* P = y_out;

  // 1) LN -> xn ; transpose -> xnT ; weight -> bf16
  ln_kernel<<<16384, 256, 0, stream>>>(x, gamma, beta, xn);
  transpose_kernel<<<dim3(256, 16), 256, 0, stream>>>(xn, xnT, 16384, 1024);
  cvt_kernel<<<1024, 256, 0, stream>>>(weight, wb);

  // 2) G = xnT @ xnT^T symmetric: upper 36 tiles, K=16384 split-16 -> P
  gemm_bt_kernel<128, 2, 2, 2><<<dim3(36, 16), 256, 0, stream>>>(
      xnT, xnT, nullptr, nullptr, nullptr, nullptr, P, nullptr, nullptr,
      16384, 1024, 5, 0.f, 0.f, 0.f);
  reduce_g_kernel<<<dim3(16, 36), 256, 0, stream>>>(P, Gb, gdiag);

  // 3) t_out = 0.9*trace + (1/32)*(W@G)  (diag of G corrected in f32)
  gemm_bt_kernel<64, 4, 2, 8><<<dim3(16, 16), 512, 0, stream>>>(
      wb, Gb, trace, weight, gdiag, nullptr, t_out, nullptr, nullptr,
      1024, 1024, 3, 0.f, 0.f, 0.f);

  // 4) y = xn @ W^T (overwrites P region), XCD-swizzled flat grid
  gemm_bt_kernel<128, 2, 2, 2><<<dim3(1024), 256, 0, stream>>>(
      xn, wb, nullptr, nullptr, nullptr, nullptr, y_out, nullptr, nullptr,
      1024, 1024, 6, 0.f, 0.f, 0.f);

  // 5) w-build + col norms -> X0 (f32+bf16) + X0^T
  wbuild_kernel<<<16, 256, 0, stream>>>(weight, t_out, wbuf, colpart);
  colfin_kernel<<<1, 256, 0, stream>>>(colpart, cscale);
  x0_kernel<<<1024, 256, 0, stream>>>(wbuf, cscale, Xf0, Xb0);
  transpose_kernel<<<dim3(16, 16), 256, 0, stream>>>(Xb0, XbT0, 1024, 1024);

  // 6) A0 = X0^T X0 (f32 + bf16) ; power iteration for sigma_max
  gemm_bt_kernel<64, 4, 2, 8><<<dim3(16, 16), 512, 0, stream>>>(
      XbT0, XbT0, nullptr, nullptr, nullptr, nullptr, Af, Ab, nullptr,
      1024, 1024, 0, 0.f, 0.f, 0.f);
  pinit_kernel<<<4, 256, 0, stream>>>(vpow, norms);
  matvec_kernel<<<64, 256, 0, stream>>>(Af, vpow, vpow + 1024, norms + 0);
  matvec_kernel<<<64, 256, 0, stream>>>(Af, vpow + 1024, vpow + 2048, norms + 1);
  matvec_kernel<<<64, 256, 0, stream>>>(Af, vpow + 2048, vpow + 3072, norms + 2);
  coefq_kernel<<<1, 1, 0, stream>>>(norms, dcoef);

  const float QA = 3.4445f, QB = -4.7750f, QC = 2.0315f;
  float* Xf[2] = {Xf0, Xf1};
  unsigned short* Xb[2] = {Xb0, Xb1};
  unsigned short* XbT[2] = {XbT0, XbT1};
  int cur = 0;

  // quintic 1 (scaled via device coeffs): B = dc0*I + dc1*A0 + dc2*A0^2 ; X <- X0@B
  gemm_bt_kernel<64, 4, 2, 8><<<dim3(16, 16), 512, 0, stream>>>(
      Ab, Ab, Af, nullptr, nullptr, dcoef, nullptr, Rb, nullptr,
      1024, 1024, 2, 0.f, 0.f, 0.f);
  gemm_bt_kernel<64, 4, 2, 8><<<dim3(16, 16), 512, 0, stream>>>(
      Xb[cur], Rb, nullptr, nullptr, nullptr, nullptr,
      Xf[cur ^ 1], Xb[cur ^ 1], XbT[cur ^ 1], 1024, 1024, 0, 0.f, 0.f, 0.f);
  cur ^= 1;

  // quintic 2,3: A = X^T X ; B = QA*I + QB*A + QC*A^2 ; X <- X@B
  for (int q = 0; q < 2; q++) {
    gemm_bt_kernel<64, 4, 2, 8><<<dim3(16, 16), 512, 0, stream>>>(
        XbT[cur], XbT[cur], nullptr, nullptr, nullptr, nullptr, Af, Ab, nullptr,
        1024, 1024, 0, 0.f, 0.f, 0.f);
    gemm_bt_kernel<64, 4, 2, 8><<<dim3(16, 16), 512, 0, stream>>>(
        Ab, Ab, Af, nullptr, nullptr, nullptr, nullptr, Rb, nullptr,
        1024, 1024, 1, QA, QB, QC);
    gemm_bt_kernel<64, 4, 2, 8><<<dim3(16, 16), 512, 0, stream>>>(
        Xb[cur], Rb, nullptr, nullptr, nullptr, nullptr,
        Xf[cur ^ 1], Xb[cur ^ 1], XbT[cur ^ 1], 1024, 1024, 0, 0.f, 0.f, 0.f);
    cur ^= 1;
  }

  // cubic 1..3: R = 0.5*(I - X^T X) ; X <- X + X@R
  for (int t = 0; t < 3; t++) {
    gemm_bt_kernel<64, 4, 2, 8><<<dim3(16, 16), 512, 0, stream>>>(
        XbT[cur], XbT[cur], nullptr, nullptr, nullptr, nullptr, nullptr, Rb,
        nullptr, 1024, 1024, 1, 0.5f, 0.f, -0.5f);
    bool last = (t == 2);
    gemm_bt_kernel<64, 4, 2, 8><<<dim3(16, 16), 512, 0, stream>>>(
        Xb[cur], Rb, Xf[cur], nullptr, nullptr, nullptr,
        last ? w_out : Xf[cur ^ 1],
        last ? (unsigned short*)nullptr : Xb[cur ^ 1],
        last ? (unsigned short*)nullptr : XbT[cur ^ 1],
        1024, 1024, 0, 0.f, 0.f, 0.f);
    cur ^= 1;
  }
}

// Round 4
// 364.548 us; speedup vs baseline: 1.5841x; 1.0334x over previous
//
#include <hip/hip_runtime.h>

// EfficientHebbian on MI355X (gfx950) — round 7.
// LN -> xn bf16 ; transpose -> xnT ; G = xnT@xnT^T symmetric-upper, split-16,
// XCD-slab-partitioned (each XCD owns 2 K-slabs = 4MB = its L2) ; reduce
// mirrors lower triangle. trace = 0.9*tr + (1/32)(W@G) fused epilogue ;
// y = xn@W^T (NT, XCD-swizzled). polar: power-iter sigma_max scale + 3
// quintic (Muon) + 3 cubic NS.
// GEMM K-loop: DEPTH-buffer ring, raw s_barrier + counted s_waitcnt vmcnt(N),
// U tiles computed per barrier window (U=2 for BM=64: 8 barriers/kernel).
//  - BM=128 big GEMMs: DEPTH=2,U=1, 256 thr, 64KB LDS -> 2 blocks/CU (TLP)
//  - BM=64 small GEMMs: DEPTH=8,U=2, 512 thr, 128KB LDS -> 4-stage cushion

typedef short short4v __attribute__((ext_vector_type(4)));
typedef short short8v __attribute__((ext_vector_type(8)));
typedef unsigned short ushort4v __attribute__((ext_vector_type(4)));
typedef unsigned short ushort8v __attribute__((ext_vector_type(8)));
typedef float f32x4 __attribute__((ext_vector_type(4)));

__device__ __forceinline__ unsigned short f2bf(float f) {
  union { float f; unsigned u; } v; v.f = f;
  unsigned r = 0x7fffu + ((v.u >> 16) & 1u);
  return (unsigned short)((v.u + r) >> 16);
}

__device__ __forceinline__ void gload_lds16(const void* g, void* l) {
  __builtin_amdgcn_global_load_lds(
      (const __attribute__((address_space(1))) void*)g,
      (__attribute__((address_space(3))) void*)l, 16, 0, 0);
}

// counted vmcnt wait; "memory" clobber = compiler fence for LDS/VMEM motion
__device__ __forceinline__ void waitvm(int n) {
  switch (n) {
    case 0: asm volatile("s_waitcnt vmcnt(0)" ::: "memory"); break;
    case 2: asm volatile("s_waitcnt vmcnt(2)" ::: "memory"); break;
    case 4: asm volatile("s_waitcnt vmcnt(4)" ::: "memory"); break;
    case 6: asm volatile("s_waitcnt vmcnt(6)" ::: "memory"); break;
    case 8: asm volatile("s_waitcnt vmcnt(8)" ::: "memory"); break;
    case 10: asm volatile("s_waitcnt vmcnt(10)" ::: "memory"); break;
    case 12: asm volatile("s_waitcnt vmcnt(12)" ::: "memory"); break;
    default: asm volatile("s_waitcnt vmcnt(0)" ::: "memory"); break;
  }
}

// ---------------- LayerNorm: x[row][1024] f32 -> xn bf16 ----------------
__global__ void __launch_bounds__(256) ln_kernel(
    const float* __restrict__ x, const float* __restrict__ gamma,
    const float* __restrict__ beta, unsigned short* __restrict__ xn) {
  __shared__ float sb[4];
  const int row = blockIdx.x;
  const int t = threadIdx.x;
  const float* xr = x + (size_t)row * 1024;
  f32x4 v = *(const f32x4*)(xr + t * 4);
  float s = v[0] + v[1] + v[2] + v[3];
  for (int m = 32; m; m >>= 1) s += __shfl_xor(s, m);
  if ((t & 63) == 0) sb[t >> 6] = s;
  __syncthreads();
  float mu = (sb[0] + sb[1] + sb[2] + sb[3]) * (1.0f / 1024.0f);
  __syncthreads();
  f32x4 d; float q = 0.f;
  for (int i = 0; i < 4; i++) { d[i] = v[i] - mu; q += d[i] * d[i]; }
  for (int m = 32; m; m >>= 1) q += __shfl_xor(q, m);
  if ((t & 63) == 0) sb[t >> 6] = q;
  __syncthreads();
  float var = (sb[0] + sb[1] + sb[2] + sb[3]) * (1.0f / 1024.0f);
  float rs = rsqrtf(var + 1e-5f);
  f32x4 g4 = *(const f32x4*)(gamma + t * 4);
  f32x4 b4 = *(const f32x4*)(beta + t * 4);
  ushort4v o;
  for (int i = 0; i < 4; i++) o[i] = f2bf(d[i] * rs * g4[i] + b4[i]);
  *(ushort4v*)(xn + (size_t)row * 1024 + t * 4) = o;
}

// ---------------- f32 -> bf16 convert ----------------
__global__ void __launch_bounds__(256) cvt_kernel(
    const float* __restrict__ in, unsigned short* __restrict__ out) {
  size_t e = ((size_t)blockIdx.x * 256 + threadIdx.x) * 4;
  f32x4 v = *(const f32x4*)(in + e);
  ushort4v o;
  for (int k = 0; k < 4; k++) o[k] = f2bf(v[k]);
  *(ushort4v*)(out + e) = o;
}

// ---------------- bf16 transpose: out[c][r] = in[r][c], 64x64 tiles ----------
__global__ void __launch_bounds__(256) transpose_kernel(
    const unsigned short* __restrict__ in, unsigned short* __restrict__ out,
    int R, int C) {
  __shared__ unsigned short tb[64][65];
  const int t = threadIdx.x;
  const int r0 = blockIdx.x * 64, c0 = blockIdx.y * 64;
#pragma unroll
  for (int p = 0; p < 2; p++) {
    int lr = p * 32 + (t >> 3);
    int lc = (t & 7) * 8;
    ushort8v v = *(const ushort8v*)(in + (size_t)(r0 + lr) * C + c0 + lc);
#pragma unroll
    for (int d = 0; d < 8; d++) tb[lr][lc + d] = v[d];
  }
  __syncthreads();
#pragma unroll
  for (int p = 0; p < 2; p++) {
    int orr = p * 32 + (t >> 3);
    int oc = (t & 7) * 8;
    ushort8v w;
#pragma unroll
    for (int d = 0; d < 8; d++) w[d] = tb[oc + d][orr];
    *(ushort8v*)(out + (size_t)(c0 + orr) * R + r0 + oc) = w;
  }
}

// ---------------- NT GEMM: C[M][N] = A[M][K] @ B[N][K]^T ----------------
// BM x BM tile, BK=64, NK=16 K-steps (Kseg must be 1024), WM x WN waves.
// XOR-swizzled LDS via pre-swizzled global src. DEPTH-buffer ring pipeline,
// U tiles per barrier window:
//   prologue: issue stages 0..DEPTH-U-1
//   group g:  waitvm(ahead*L) [tiles Ug..Ug+U-1 complete; ahead stages
//             stay in flight] ; s_barrier ; issue stages Ug+DEPTH-U..+U-1
//             [those buffers were consumed at group g-1, barrier proves it];
//             ds_read+MFMA tiles Ug..Ug+U-1
// modes: 0: v=acc (+addF if set)
//        1: v = c0*(r==c) + c1*addF + c2*acc        (immediate coeffs)
//        2: v = dcoef[0]*(r==c) + dcoef[1]*addF + dcoef[2]*acc
//        3: v = 0.9*addF + (1/32)*(acc + addF2*dvec[c])   (trace epilogue)
//        5: symmetric-upper partial, XCD-slab map (BM=128): flat 576 grid,
//           c=id&7 (XCD), s=id>>3: zseg = 2c+(s>=36), tile idx = s mod 36
//           (each XCD works only K-slabs {2c,2c+1} = 4MB = its L2);
//           outF += zseg<<20
//        6: as mode 0 but flat 1D grid with XCD swizzle (M=128,N=8 tiles):
//           c=l&7 (XCD), s=l>>3: m-tile = c*16+(s>>3), n-tile = s&7
// outBT (if set, BM=64 only): writes bf16 transposed tile via LDS.
template <int BM, int WM, int WN, int DEPTH, int U>
__global__ void __launch_bounds__(WM * WN * 64, 2) gemm_bt_kernel(
    const unsigned short* __restrict__ A, const unsigned short* __restrict__ B,
    const float* __restrict__ addF, const float* __restrict__ addF2,
    const float* __restrict__ dvec, const float* __restrict__ dcoef,
    float* __restrict__ outF, unsigned short* __restrict__ outB,
    unsigned short* __restrict__ outBT,
    int ldk, int Kseg, int mode, float c0, float c1, float c2) {
  constexpr int WAVES = WM * WN;
  constexpr int NT = WAVES * 64;
  constexpr int FMm = BM / (16 * WM);
  constexpr int FMn = BM / (16 * WN);
  constexpr int CPW = BM / (8 * WAVES);  // 1KB chunks per wave per operand
  constexpr int L = 2 * CPW;             // vmem loads per wave per stage
  constexpr int BUFS = 2 * BM * 64;      // shorts per buffer (A then B)
  constexpr int NK = 16;                 // Kseg == 1024 always
  constexpr int NG = NK / U;
  __shared__ __align__(16) unsigned short lds[DEPTH * BUFS];
  const int tid = threadIdx.x, lane = tid & 63, wv = tid >> 6;
  const int wm = wv / WN, wn = wv % WN;

  int m0, n0, kb = 0, zseg = 0;
  if (mode == 5) {
    int id = blockIdx.x;
    int c = id & 7, s = id >> 3;
    zseg = c * 2 + (s >= 36 ? 1 : 0);
    int tt = (s >= 36) ? s - 36 : s;
    int ti = 0;
    while (tt >= 8 - ti) { tt -= 8 - ti; ++ti; }
    m0 = ti * BM; n0 = (ti + tt) * BM;
    kb = zseg * Kseg;
  } else if (mode == 6) {
    int l = blockIdx.x;
    int c = l & 7, s = l >> 3;
    m0 = (c * 16 + (s >> 3)) * BM;
    n0 = (s & 7) * BM;
  } else {
    m0 = blockIdx.x * BM; n0 = blockIdx.y * BM;
  }

  const int srow = lane >> 3;
  const int skoff = 8 * ((lane & 7) ^ srow);  // pre-swizzled global k-offset

  f32x4 acc[FMm][FMn];
  for (int a = 0; a < FMm; a++)
    for (int b = 0; b < FMn; b++) acc[a][b] = (f32x4){0.f, 0.f, 0.f, 0.f};

  auto stage = [&](int buf, int kk) {
#pragma unroll
    for (int ci = 0; ci < CPW; ci++) {
      int ch = wv * CPW + ci;
      const unsigned short* ga = A + (size_t)(m0 + 8 * ch + srow) * ldk + kk + skoff;
      const unsigned short* gb = B + (size_t)(n0 + 8 * ch + srow) * ldk + kk + skoff;
      char* lb = (char*)(lds + buf * BUFS);
      gload_lds16(ga, lb + ch * 1024);
      gload_lds16(gb, lb + BM * 128 + ch * 1024);
    }
  };

  // prologue: DEPTH-U stages in flight
#pragma unroll
  for (int d = 0; d < DEPTH - U; ++d) stage(d, kb + (d << 6));

#pragma unroll
  for (int g = 0; g < NG; ++g) {
    int done = U * g + U;                       // tiles that must be complete
    int issued = DEPTH - U + U * g;
    if (issued > NK) issued = NK;
    int ahead = issued - done;                  // stages allowed in flight
    waitvm(ahead * L);
    __builtin_amdgcn_s_barrier();
#pragma unroll
    for (int u = 0; u < U; ++u) {
      int ts = U * g + (DEPTH - U) + u;
      if (ts < NK) stage(ts % DEPTH, kb + (ts << 6));
    }

    const int g16 = lane >> 4;
#pragma unroll
    for (int u = 0; u < U; ++u) {
      const unsigned short* As = lds + ((U * g + u) % DEPTH) * BUFS;
      const unsigned short* Bs = As + BM * 64;
#pragma unroll
      for (int ks = 0; ks < 2; ks++) {
        short8v af[FMm], bfr[FMn];
#pragma unroll
        for (int fm = 0; fm < FMm; fm++) {
          int row = wm * (BM / WM) + fm * 16 + (lane & 15);
          int swz = (row & 7) << 4;
          const char* rp = (const char*)As + row * 128;
          int o = ks * 64 + g16 * 8;
          short4v lo = *(const short4v*)(rp + (o ^ swz));
          short4v hi = *(const short4v*)(rp + ((o + 32) ^ swz));
          af[fm] = __builtin_shufflevector(lo, hi, 0, 1, 2, 3, 4, 5, 6, 7);
        }
#pragma unroll
        for (int fn = 0; fn < FMn; fn++) {
          int row = wn * (BM / WN) + fn * 16 + (lane & 15);
          int swz = (row & 7) << 4;
          const char* rp = (const char*)Bs + row * 128;
          int o = ks * 64 + g16 * 8;
          short4v lo = *(const short4v*)(rp + (o ^ swz));
          short4v hi = *(const short4v*)(rp + ((o + 32) ^ swz));
          bfr[fn] = __builtin_shufflevector(lo, hi, 0, 1, 2, 3, 4, 5, 6, 7);
        }
#pragma unroll
        for (int fm = 0; fm < FMm; fm++)
#pragma unroll
          for (int fn = 0; fn < FMn; fn++)
            acc[fm][fn] = __builtin_amdgcn_mfma_f32_16x16x32_bf16(
                af[fm], bfr[fn], acc[fm][fn], 0, 0, 0);
      }
    }
  }

  float* of = outF;
  if (mode == 5 && of) of += ((size_t)zseg << 20);
  float dc0 = 0.f, dc1 = 0.f, dc2 = 0.f;
  if (mode == 2) { dc0 = dcoef[0]; dc1 = dcoef[1]; dc2 = dcoef[2]; }

#pragma unroll
  for (int fm = 0; fm < FMm; fm++) {
    int r0 = m0 + wm * (BM / WM) + fm * 16 + (lane >> 4) * 4;
#pragma unroll
    for (int fn = 0; fn < FMn; fn++) {
      int c = n0 + wn * (BM / WN) + fn * 16 + (lane & 15);
#pragma unroll
      for (int j = 0; j < 4; j++) {
        int r = r0 + j;
        size_t off = (size_t)r * 1024 + c;
        float v = acc[fm][fn][j];
        if (mode == 0 || mode == 6) {
          if (addF) v += addF[off];
        } else if (mode == 1) {
          v = c0 * (r == c ? 1.f : 0.f) + (addF ? c1 * addF[off] : 0.f) + c2 * v;
        } else if (mode == 2) {
          v = dc0 * (r == c ? 1.f : 0.f) + dc1 * addF[off] + dc2 * v;
        } else if (mode == 3) {
          v = 0.9f * addF[off] + 0.03125f * (v + addF2[off] * dvec[c]);
        }
        if (of) of[off] = v;
        if (outB) outB[off] = f2bf(v);
        acc[fm][fn][j] = v;
      }
    }
  }

  // optional transposed bf16 output (used by BM=64 NS X-updates only)
  if (outBT) {
    constexpr int LDT = BM + 1;
    __syncthreads();
#pragma unroll
    for (int fm = 0; fm < FMm; fm++) {
      int lr0 = wm * (BM / WM) + fm * 16 + (lane >> 4) * 4;
#pragma unroll
      for (int fn = 0; fn < FMn; fn++) {
        int lc = wn * (BM / WN) + fn * 16 + (lane & 15);
#pragma unroll
        for (int j = 0; j < 4; j++)
          lds[(lr0 + j) * LDT + lc] = f2bf(acc[fm][fn][j]);
      }
    }
    __syncthreads();
    for (int e = tid * 8; e < BM * BM; e += NT * 8) {
      int orr = e / BM;          // output row = col of tile
      int oc = e % BM;           // output col base = row of tile
      ushort8v w;
#pragma unroll
      for (int d = 0; d < 8; d++) w[d] = lds[(oc + d) * LDT + orr];
      *(ushort8v*)(outBT + (size_t)(n0 + orr) * 1024 + m0 + oc) = w;
    }
  }
}

// ---- reduce G: sum 16 partials over upper 128^2 tiles -> Gb bf16, mirror
// lower triangle, diag zeroed + gdiag. grid: dim3(16 subblocks, 36 tiles).
__global__ void __launch_bounds__(256) reduce_g_kernel(
    const float* __restrict__ P, unsigned short* __restrict__ Gb,
    float* __restrict__ gdiag) {
  int tt = blockIdx.y, ti = 0;
  while (tt >= 8 - ti) { tt -= 8 - ti; ++ti; }
  const int tj = ti + tt;
  const int eloc = (blockIdx.x * 256 + threadIdx.x) * 4;
  const int lr = eloc >> 7, lc = eloc & 127;
  const int r = ti * 128 + lr, c0 = tj * 128 + lc;
  const size_t off = (size_t)r * 1024 + c0;
  f32x4 s = *(const f32x4*)(P + off);
#pragma unroll
  for (int z = 1; z < 16; z++)
    s += *(const f32x4*)(P + ((size_t)z << 20) + off);
  ushort4v o;
#pragma unroll
  for (int q = 0; q < 4; q++) {
    int c = c0 + q;
    unsigned short b = f2bf(s[q]);
    if (ti == tj && c == r) { gdiag[r] = s[q]; o[q] = 0; }
    else o[q] = b;
    if (ti != tj) Gb[(size_t)c * 1024 + r] = b;  // mirror into lower triangle
  }
  *(ushort4v*)(Gb + off) = o;
}

// ---------------- w = weight + 0.01*clip(trace,-1,1); per-column sumsq -------
__global__ void __launch_bounds__(256) wbuild_kernel(
    const float* __restrict__ weight, const float* __restrict__ tout,
    float* __restrict__ w, float* __restrict__ colpart) {
  int t = threadIdx.x, blk = blockIdx.x;
  float cs[4] = {0.f, 0.f, 0.f, 0.f};
  for (int r = 0; r < 64; r++) {
    size_t row = (size_t)blk * 64 + r;
    for (int cc = 0; cc < 4; cc++) {
      size_t idx = row * 1024 + cc * 256 + t;
      float u = tout[idx];
      u = fminf(fmaxf(u, -1.f), 1.f);
      float wv = weight[idx] + 0.01f * u;
      w[idx] = wv;
      cs[cc] += wv * wv;
    }
  }
  for (int cc = 0; cc < 4; cc++) colpart[blk * 1024 + cc * 256 + t] = cs[cc];
}

// ---------------- cscale[j] = 1/max(colnorm_j,1e-3) (no fro) ----------------
__global__ void __launch_bounds__(256) colfin_kernel(
    const float* __restrict__ colpart, float* __restrict__ cscale) {
  int t = threadIdx.x;
  for (int q = 0; q < 4; q++) {
    int j = t * 4 + q;
    float s = 0.f;
    for (int b = 0; b < 16; b++) s += colpart[b * 1024 + j];
    float cn = fmaxf(sqrtf(s), 1e-3f);
    cscale[j] = 1.f / cn;
  }
}

// ---------------- X0 = w * cscale (f32 + bf16) ----------------
__global__ void __launch_bounds__(256) x0_kernel(
    const float* __restrict__ w, const float* __restrict__ cscale,
    float* __restrict__ X, unsigned short* __restrict__ Xb) {
  size_t e = ((size_t)blockIdx.x * 256 + threadIdx.x) * 4;
  int j = (int)(e & 1023);
  f32x4 wv = *(const f32x4*)(w + e);
  f32x4 cs = *(const f32x4*)(cscale + j);
  f32x4 xo; ushort4v xb;
  for (int q = 0; q < 4; q++) { xo[q] = wv[q] * cs[q]; xb[q] = f2bf(xo[q]); }
  *(f32x4*)(X + e) = xo;
  *(ushort4v*)(Xb + e) = xb;
}

// ---------------- power-iteration init: v0 = +/-1 hash; zero norms ----------
__global__ void __launch_bounds__(256) pinit_kernel(
    float* __restrict__ v0, float* __restrict__ norms) {
  int i = blockIdx.x * 256 + threadIdx.x;
  unsigned h = (unsigned)i * 2654435761u;
  v0[i] = ((h >> 16) & 1u) ? 1.f : -1.f;
  if (blockIdx.x == 0 && threadIdx.x < 4) norms[threadIdx.x] = 0.f;
}

// ---------------- matvec: vout = A vin (A f32 1024x1024); ||vout||^2 += norm --
__global__ void __launch_bounds__(256) matvec_kernel(
    const float* __restrict__ A, const float* __restrict__ vin,
    float* __restrict__ vout, float* __restrict__ normsq) {
  __shared__ float red[4];
  int t = threadIdx.x;
  int r0 = blockIdx.x * 16;
  f32x4 vv = *(const f32x4*)(vin + t * 4);
  float sq = 0.f;
  for (int r = 0; r < 16; r++) {
    f32x4 a = *(const f32x4*)(A + (size_t)(r0 + r) * 1024 + t * 4);
    float d = a[0] * vv[0] + a[1] * vv[1] + a[2] * vv[2] + a[3] * vv[3];
    for (int m = 32; m; m >>= 1) d += __shfl_xor(d, m);
    if ((t & 63) == 0) red[t >> 6] = d;
    __syncthreads();
    if (t == 0) {
      float s = red[0] + red[1] + red[2] + red[3];
      vout[r0 + r] = s;
      sq += s * s;
    }
    __syncthreads();
  }
  if (t == 0) atomicAdd(normsq, sq);
}

// ---------------- quintic-1 coefficients from power-iter norms ----------------
__global__ void coefq_kernel(const float* __restrict__ norms,
                             float* __restrict__ dcoef) {
  const float QA = 3.4445f, QB = -4.7750f, QC = 2.0315f;
  float n1 = fmaxf(norms[1], 1e-30f), n2 = fmaxf(norms[2], 1e-30f);
  float lam = sqrtf(n2 / n1);            // ~ sigma_max^2
  float s = sqrtf(fmaxf(lam, 1e-8f)) / 0.95f;
  s = fmaxf(s, 1e-3f);
  float s2 = s * s;
  dcoef[0] = QA / s;
  dcoef[1] = QB / (s * s2);
  dcoef[2] = QC / (s * s2 * s2);
}

extern "C" void kernel_launch(void* const* d_in, const int* in_sizes, int n_in,
                              void* d_out, int out_size, void* d_ws, size_t ws_size,
                              hipStream_t stream) {
  const float* x      = (const float*)d_in[0];
  const float* weight = (const float*)d_in[1];
  const float* gamma  = (const float*)d_in[2];
  const float* beta   = (const float*)d_in[3];
  const float* trace  = (const float*)d_in[4];

  float* y_out = (float*)d_out;                  // [16384,1024]
  float* w_out = y_out + (size_t)16777216;       // [1024,1024]
  float* t_out = w_out + (size_t)1048576;        // [1024,1024]

  const size_t MB = 1048576;
  char* ws = (char*)d_ws;
  unsigned short* xn   = (unsigned short*)(ws);            // 32MB
  unsigned short* xnT  = (unsigned short*)(ws + 32 * MB);  // 32MB
  float* Xf0           = (float*)(ws + 64 * MB);           // 4MB
  float* Xf1           = (float*)(ws + 68 * MB);           // 4MB
  float* wbuf          = (float*)(ws + 72 * MB);           // 4MB (reused as Af)
  float* Af            = (float*)(ws + 72 * MB);           //   alias (wbuf dead)
  unsigned short* Xb0  = (unsigned short*)(ws + 76 * MB);  // 2MB
  unsigned short* Xb1  = (unsigned short*)(ws + 78 * MB);  // 2MB
  unsigned short* XbT0 = (unsigned short*)(ws + 80 * MB);  // 2MB
  unsigned short* XbT1 = (unsigned short*)(ws + 82 * MB);  // 2MB
  unsigned short* Ab   = (unsigned short*)(ws + 84 * MB);  // 2MB
  unsigned short* Rb   = (unsigned short*)(ws + 86 * MB);  // 2MB (also quintic B)
  unsigned short* Gb   = (unsigned short*)(ws + 88 * MB);  // 2MB
  unsigned short* wb   = (unsigned short*)(ws + 90 * MB);  // 2MB
  float* colpart       = (float*)(ws + 92 * MB);           // 64KB
  float* cscale        = (float*)(ws + 92 * MB + 65536);   // 4KB
  float* gdiag         = (float*)(ws + 92 * MB + 69632);   // 4KB
  float* vpow          = (float*)(ws + 92 * MB + 73728);   // 4 x 4KB (v0..v3)
  float* norms         = (float*)(ws + 92 * MB + 90112);   // 64B
  float* dcoef         = (float*)(ws + 92 * MB + 90176);   // 64B

  // G partials live in the (not yet written) y region of d_out: 16 x 4MB = 64MB
  float* P = y_out;

  // 1) LN -> xn ; transpose -> xnT ; weight -> bf16
  ln_kernel<<<16384, 256, 0, stream>>>(x, gamma, beta, xn);
  transpose_kernel<<<dim3(256, 16), 256, 0, stream>>>(xn, xnT, 16384, 1024);
  cvt_kernel<<<1024, 256, 0, stream>>>(weight, wb);

  // 2) G = xnT @ xnT^T symmetric: upper 36 tiles, K=16384 split-16 -> P
  //    flat 576 grid, XCD-slab mapping (mode 5)
  gemm_bt_kernel<128, 2, 2, 2, 1><<<dim3(576), 256, 0, stream>>>(
      xnT, xnT, nullptr, nullptr, nullptr, nullptr, P, nullptr, nullptr,
      16384, 1024, 5, 0.f, 0.f, 0.f);
  reduce_g_kernel<<<dim3(16, 36), 256, 0, stream>>>(P, Gb, gdiag);

  // 3) t_out = 0.9*trace + (1/32)*(W@G)  (diag of G corrected in f32)
  gemm_bt_kernel<64, 4, 2, 8, 2><<<dim3(16, 16), 512, 0, stream>>>(
      wb, Gb, trace, weight, gdiag, nullptr, t_out, nullptr, nullptr,
      1024, 1024, 3, 0.f, 0.f, 0.f);

  // 4) y = xn @ W^T (overwrites P region), XCD-swizzled flat grid
  gemm_bt_kernel<128, 2, 2, 2, 1><<<dim3(1024), 256, 0, stream>>>(
      xn, wb, nullptr, nullptr, nullptr, nullptr, y_out, nullptr, nullptr,
      1024, 1024, 6, 0.f, 0.f, 0.f);

  // 5) w-build + col norms -> X0 (f32+bf16) + X0^T
  wbuild_kernel<<<16, 256, 0, stream>>>(weight, t_out, wbuf, colpart);
  colfin_kernel<<<1, 256, 0, stream>>>(colpart, cscale);
  x0_kernel<<<1024, 256, 0, stream>>>(wbuf, cscale, Xf0, Xb0);
  transpose_kernel<<<dim3(16, 16), 256, 0, stream>>>(Xb0, XbT0, 1024, 1024);

  // 6) A0 = X0^T X0 (f32 + bf16) ; power iteration for sigma_max
  gemm_bt_kernel<64, 4, 2, 8, 2><<<dim3(16, 16), 512, 0, stream>>>(
      XbT0, XbT0, nullptr, nullptr, nullptr, nullptr, Af, Ab, nullptr,
      1024, 1024, 0, 0.f, 0.f, 0.f);
  pinit_kernel<<<4, 256, 0, stream>>>(vpow, norms);
  matvec_kernel<<<64, 256, 0, stream>>>(Af, vpow, vpow + 1024, norms + 0);
  matvec_kernel<<<64, 256, 0, stream>>>(Af, vpow + 1024, vpow + 2048, norms + 1);
  matvec_kernel<<<64, 256, 0, stream>>>(Af, vpow + 2048, vpow + 3072, norms + 2);
  coefq_kernel<<<1, 1, 0, stream>>>(norms, dcoef);

  const float QA = 3.4445f, QB = -4.7750f, QC = 2.0315f;
  float* Xf[2] = {Xf0, Xf1};
  unsigned short* Xb[2] = {Xb0, Xb1};
  unsigned short* XbT[2] = {XbT0, XbT1};
  int cur = 0;

  // quintic 1 (scaled via device coeffs): B = dc0*I + dc1*A0 + dc2*A0^2 ; X <- X0@B
  gemm_bt_kernel<64, 4, 2, 8, 2><<<dim3(16, 16), 512, 0, stream>>>(
      Ab, Ab, Af, nullptr, nullptr, dcoef, nullptr, Rb, nullptr,
      1024, 1024, 2, 0.f, 0.f, 0.f);
  gemm_bt_kernel<64, 4, 2, 8, 2><<<dim3(16, 16), 512, 0, stream>>>(
      Xb[cur], Rb, nullptr, nullptr, nullptr, nullptr,
      Xf[cur ^ 1], Xb[cur ^ 1], XbT[cur ^ 1], 1024, 1024, 0, 0.f, 0.f, 0.f);
  cur ^= 1;

  // quintic 2,3: A = X^T X ; B = QA*I + QB*A + QC*A^2 ; X <- X@B
  for (int q = 0; q < 2; q++) {
    gemm_bt_kernel<64, 4, 2, 8, 2><<<dim3(16, 16), 512, 0, stream>>>(
        XbT[cur], XbT[cur], nullptr, nullptr, nullptr, nullptr, Af, Ab, nullptr,
        1024, 1024, 0, 0.f, 0.f, 0.f);
    gemm_bt_kernel<64, 4, 2, 8, 2><<<dim3(16, 16), 512, 0, stream>>>(
        Ab, Ab, Af, nullptr, nullptr, nullptr, nullptr, Rb, nullptr,
        1024, 1024, 1, QA, QB, QC);
    gemm_bt_kernel<64, 4, 2, 8, 2><<<dim3(16, 16), 512, 0, stream>>>(
        Xb[cur], Rb, nullptr, nullptr, nullptr, nullptr,
        Xf[cur ^ 1], Xb[cur ^ 1], XbT[cur ^ 1], 1024, 1024, 0, 0.f, 0.f, 0.f);
    cur ^= 1;
  }

  // cubic 1..3: R = 0.5*(I - X^T X) ; X <- X + X@R
  for (int t = 0; t < 3; t++) {
    gemm_bt_kernel<64, 4, 2, 8, 2><<<dim3(16, 16), 512, 0, stream>>>(
        XbT[cur], XbT[cur], nullptr, nullptr, nullptr, nullptr, nullptr, Rb,
        nullptr, 1024, 1024, 1, 0.5f, 0.f, -0.5f);
    bool last = (t == 2);
    gemm_bt_kernel<64, 4, 2, 8, 2><<<dim3(16, 16), 512, 0, stream>>>(
        Xb[cur], Rb, Xf[cur], nullptr, nullptr, nullptr,
        last ? w_out : Xf[cur ^ 1],
        last ? (unsigned short*)nullptr : Xb[cur ^ 1],
        last ? (unsigned short*)nullptr : XbT[cur ^ 1],
        1024, 1024, 0, 0.f, 0.f, 0.f);
    cur ^= 1;
  }
}

// Round 5
// 364.346 us; speedup vs baseline: 1.5850x; 1.0006x over previous
//
#include <hip/hip_runtime.h>

// EfficientHebbian on MI355X (gfx950) — round 8.
// LN -> xn bf16 ; transpose -> xnT ; G = xnT@xnT^T symmetric-upper, split-16,
// XCD-slab-partitioned ; reduce mirrors lower triangle.
// trace = 0.9*tr + (1/32)(W@G) fused epilogue ; y = xn@W^T (XCD-swizzled).
// polar: power-iter sigma_max scale + 3 quintic (Muon) + 3 cubic NS.
// GEMM K-loop: DEPTH-buffer ring, raw s_barrier + counted s_waitcnt vmcnt(N),
// U tiles per barrier window.
//  - BM=128 big GEMMs: 8 waves (2x4), DEPTH=2, 512 thr, 64KB LDS ->
//    2 blocks/CU = 4 waves/SIMD (TLP latency hiding; r5 failed at 1 blk/CU,
//    this keeps residency while doubling waves)
//  - BM=64 small GEMMs: DEPTH=8,U=2, 512 thr, 128KB LDS
// Fusions: colfin folded into wbuild (atomics, zeroed by cvt);
// x0 + transpose fused into tile-based x0t_kernel.

typedef short short4v __attribute__((ext_vector_type(4)));
typedef short short8v __attribute__((ext_vector_type(8)));
typedef unsigned short ushort4v __attribute__((ext_vector_type(4)));
typedef unsigned short ushort8v __attribute__((ext_vector_type(8)));
typedef float f32x4 __attribute__((ext_vector_type(4)));

__device__ __forceinline__ unsigned short f2bf(float f) {
  union { float f; unsigned u; } v; v.f = f;
  unsigned r = 0x7fffu + ((v.u >> 16) & 1u);
  return (unsigned short)((v.u + r) >> 16);
}

__device__ __forceinline__ void gload_lds16(const void* g, void* l) {
  __builtin_amdgcn_global_load_lds(
      (const __attribute__((address_space(1))) void*)g,
      (__attribute__((address_space(3))) void*)l, 16, 0, 0);
}

// counted vmcnt wait; "memory" clobber = compiler fence for LDS/VMEM motion
__device__ __forceinline__ void waitvm(int n) {
  switch (n) {
    case 0: asm volatile("s_waitcnt vmcnt(0)" ::: "memory"); break;
    case 2: asm volatile("s_waitcnt vmcnt(2)" ::: "memory"); break;
    case 4: asm volatile("s_waitcnt vmcnt(4)" ::: "memory"); break;
    case 6: asm volatile("s_waitcnt vmcnt(6)" ::: "memory"); break;
    case 8: asm volatile("s_waitcnt vmcnt(8)" ::: "memory"); break;
    case 10: asm volatile("s_waitcnt vmcnt(10)" ::: "memory"); break;
    case 12: asm volatile("s_waitcnt vmcnt(12)" ::: "memory"); break;
    default: asm volatile("s_waitcnt vmcnt(0)" ::: "memory"); break;
  }
}

// ---------------- LayerNorm: x[row][1024] f32 -> xn bf16 ----------------
__global__ void __launch_bounds__(256) ln_kernel(
    const float* __restrict__ x, const float* __restrict__ gamma,
    const float* __restrict__ beta, unsigned short* __restrict__ xn) {
  __shared__ float sb[4];
  const int row = blockIdx.x;
  const int t = threadIdx.x;
  const float* xr = x + (size_t)row * 1024;
  f32x4 v = *(const f32x4*)(xr + t * 4);
  float s = v[0] + v[1] + v[2] + v[3];
  for (int m = 32; m; m >>= 1) s += __shfl_xor(s, m);
  if ((t & 63) == 0) sb[t >> 6] = s;
  __syncthreads();
  float mu = (sb[0] + sb[1] + sb[2] + sb[3]) * (1.0f / 1024.0f);
  __syncthreads();
  f32x4 d; float q = 0.f;
  for (int i = 0; i < 4; i++) { d[i] = v[i] - mu; q += d[i] * d[i]; }
  for (int m = 32; m; m >>= 1) q += __shfl_xor(q, m);
  if ((t & 63) == 0) sb[t >> 6] = q;
  __syncthreads();
  float var = (sb[0] + sb[1] + sb[2] + sb[3]) * (1.0f / 1024.0f);
  float rs = rsqrtf(var + 1e-5f);
  f32x4 g4 = *(const f32x4*)(gamma + t * 4);
  f32x4 b4 = *(const f32x4*)(beta + t * 4);
  ushort4v o;
  for (int i = 0; i < 4; i++) o[i] = f2bf(d[i] * rs * g4[i] + b4[i]);
  *(ushort4v*)(xn + (size_t)row * 1024 + t * 4) = o;
}

// ------- f32 -> bf16 convert; block 0 also zeroes colsumsq[1024] -------
__global__ void __launch_bounds__(256) cvt_kernel(
    const float* __restrict__ in, unsigned short* __restrict__ out,
    float* __restrict__ zbuf) {
  if (blockIdx.x == 0) {
    f32x4 z = (f32x4){0.f, 0.f, 0.f, 0.f};
    ((f32x4*)zbuf)[threadIdx.x] = z;
  }
  size_t e = ((size_t)blockIdx.x * 256 + threadIdx.x) * 4;
  f32x4 v = *(const f32x4*)(in + e);
  ushort4v o;
  for (int k = 0; k < 4; k++) o[k] = f2bf(v[k]);
  *(ushort4v*)(out + e) = o;
}

// ---------------- bf16 transpose: out[c][r] = in[r][c], 64x64 tiles ----------
__global__ void __launch_bounds__(256) transpose_kernel(
    const unsigned short* __restrict__ in, unsigned short* __restrict__ out,
    int R, int C) {
  __shared__ unsigned short tb[64][65];
  const int t = threadIdx.x;
  const int r0 = blockIdx.x * 64, c0 = blockIdx.y * 64;
#pragma unroll
  for (int p = 0; p < 2; p++) {
    int lr = p * 32 + (t >> 3);
    int lc = (t & 7) * 8;
    ushort8v v = *(const ushort8v*)(in + (size_t)(r0 + lr) * C + c0 + lc);
#pragma unroll
    for (int d = 0; d < 8; d++) tb[lr][lc + d] = v[d];
  }
  __syncthreads();
#pragma unroll
  for (int p = 0; p < 2; p++) {
    int orr = p * 32 + (t >> 3);
    int oc = (t & 7) * 8;
    ushort8v w;
#pragma unroll
    for (int d = 0; d < 8; d++) w[d] = tb[oc + d][orr];
    *(ushort8v*)(out + (size_t)(c0 + orr) * R + r0 + oc) = w;
  }
}

// ---------------- NT GEMM: C[M][N] = A[M][K] @ B[N][K]^T ----------------
// BM x BM tile, BK=64, NK=16 K-steps (Kseg must be 1024), WM x WN waves.
// XOR-swizzled LDS via pre-swizzled global src. DEPTH-buffer ring pipeline,
// U tiles per barrier window (see r7 comment).
// modes: 0: v=acc (+addF if set)
//        1: v = c0*(r==c) + c1*addF + c2*acc        (immediate coeffs)
//        2: v = dcoef[0]*(r==c) + dcoef[1]*addF + dcoef[2]*acc
//        3: v = 0.9*addF + (1/32)*(acc + addF2*dvec[c])   (trace epilogue)
//        5: symmetric-upper partial, XCD-slab map (BM=128): flat 576 grid,
//           c=id&7 (XCD), s=id>>3: zseg = 2c+(s>=36), tile idx = s mod 36;
//           outF += zseg<<20
//        6: as mode 0 but flat 1D grid with XCD swizzle (M=128,N=8 tiles):
//           c=l&7 (XCD), s=l>>3: m-tile = c*16+(s>>3), n-tile = s&7
// outBT (if set, BM=64 only): writes bf16 transposed tile via LDS.
template <int BM, int WM, int WN, int DEPTH, int U>
__global__ void __launch_bounds__(WM * WN * 64, (WM * WN) / 2) gemm_bt_kernel(
    const unsigned short* __restrict__ A, const unsigned short* __restrict__ B,
    const float* __restrict__ addF, const float* __restrict__ addF2,
    const float* __restrict__ dvec, const float* __restrict__ dcoef,
    float* __restrict__ outF, unsigned short* __restrict__ outB,
    unsigned short* __restrict__ outBT,
    int ldk, int Kseg, int mode, float c0, float c1, float c2) {
  constexpr int WAVES = WM * WN;
  constexpr int NT = WAVES * 64;
  constexpr int FMm = BM / (16 * WM);
  constexpr int FMn = BM / (16 * WN);
  constexpr int CPW = BM / (8 * WAVES);  // 1KB chunks per wave per operand
  constexpr int L = 2 * CPW;             // vmem loads per wave per stage
  constexpr int BUFS = 2 * BM * 64;      // shorts per buffer (A then B)
  constexpr int NK = 16;                 // Kseg == 1024 always
  constexpr int NG = NK / U;
  __shared__ __align__(16) unsigned short lds[DEPTH * BUFS];
  const int tid = threadIdx.x, lane = tid & 63, wv = tid >> 6;
  const int wm = wv / WN, wn = wv % WN;

  int m0, n0, kb = 0, zseg = 0;
  if (mode == 5) {
    int id = blockIdx.x;
    int c = id & 7, s = id >> 3;
    zseg = c * 2 + (s >= 36 ? 1 : 0);
    int tt = (s >= 36) ? s - 36 : s;
    int ti = 0;
    while (tt >= 8 - ti) { tt -= 8 - ti; ++ti; }
    m0 = ti * BM; n0 = (ti + tt) * BM;
    kb = zseg * Kseg;
  } else if (mode == 6) {
    int l = blockIdx.x;
    int c = l & 7, s = l >> 3;
    m0 = (c * 16 + (s >> 3)) * BM;
    n0 = (s & 7) * BM;
  } else {
    m0 = blockIdx.x * BM; n0 = blockIdx.y * BM;
  }

  const int srow = lane >> 3;
  const int skoff = 8 * ((lane & 7) ^ srow);  // pre-swizzled global k-offset

  f32x4 acc[FMm][FMn];
  for (int a = 0; a < FMm; a++)
    for (int b = 0; b < FMn; b++) acc[a][b] = (f32x4){0.f, 0.f, 0.f, 0.f};

  auto stage = [&](int buf, int kk) {
#pragma unroll
    for (int ci = 0; ci < CPW; ci++) {
      int ch = wv * CPW + ci;
      const unsigned short* ga = A + (size_t)(m0 + 8 * ch + srow) * ldk + kk + skoff;
      const unsigned short* gb = B + (size_t)(n0 + 8 * ch + srow) * ldk + kk + skoff;
      char* lb = (char*)(lds + buf * BUFS);
      gload_lds16(ga, lb + ch * 1024);
      gload_lds16(gb, lb + BM * 128 + ch * 1024);
    }
  };

  // prologue: DEPTH-U stages in flight
#pragma unroll
  for (int d = 0; d < DEPTH - U; ++d) stage(d, kb + (d << 6));

#pragma unroll
  for (int g = 0; g < NG; ++g) {
    int done = U * g + U;                       // tiles that must be complete
    int issued = DEPTH - U + U * g;
    if (issued > NK) issued = NK;
    int ahead = issued - done;                  // stages allowed in flight
    waitvm(ahead * L);
    __builtin_amdgcn_s_barrier();
#pragma unroll
    for (int u = 0; u < U; ++u) {
      int ts = U * g + (DEPTH - U) + u;
      if (ts < NK) stage(ts % DEPTH, kb + (ts << 6));
    }

    const int g16 = lane >> 4;
#pragma unroll
    for (int u = 0; u < U; ++u) {
      const unsigned short* As = lds + ((U * g + u) % DEPTH) * BUFS;
      const unsigned short* Bs = As + BM * 64;
#pragma unroll
      for (int ks = 0; ks < 2; ks++) {
        short8v af[FMm], bfr[FMn];
#pragma unroll
        for (int fm = 0; fm < FMm; fm++) {
          int row = wm * (BM / WM) + fm * 16 + (lane & 15);
          int swz = (row & 7) << 4;
          const char* rp = (const char*)As + row * 128;
          int o = ks * 64 + g16 * 8;
          short4v lo = *(const short4v*)(rp + (o ^ swz));
          short4v hi = *(const short4v*)(rp + ((o + 32) ^ swz));
          af[fm] = __builtin_shufflevector(lo, hi, 0, 1, 2, 3, 4, 5, 6, 7);
        }
#pragma unroll
        for (int fn = 0; fn < FMn; fn++) {
          int row = wn * (BM / WN) + fn * 16 + (lane & 15);
          int swz = (row & 7) << 4;
          const char* rp = (const char*)Bs + row * 128;
          int o = ks * 64 + g16 * 8;
          short4v lo = *(const short4v*)(rp + (o ^ swz));
          short4v hi = *(const short4v*)(rp + ((o + 32) ^ swz));
          bfr[fn] = __builtin_shufflevector(lo, hi, 0, 1, 2, 3, 4, 5, 6, 7);
        }
#pragma unroll
        for (int fm = 0; fm < FMm; fm++)
#pragma unroll
          for (int fn = 0; fn < FMn; fn++)
            acc[fm][fn] = __builtin_amdgcn_mfma_f32_16x16x32_bf16(
                af[fm], bfr[fn], acc[fm][fn], 0, 0, 0);
      }
    }
  }

  float* of = outF;
  if (mode == 5 && of) of += ((size_t)zseg << 20);
  float dc0 = 0.f, dc1 = 0.f, dc2 = 0.f;
  if (mode == 2) { dc0 = dcoef[0]; dc1 = dcoef[1]; dc2 = dcoef[2]; }

#pragma unroll
  for (int fm = 0; fm < FMm; fm++) {
    int r0 = m0 + wm * (BM / WM) + fm * 16 + (lane >> 4) * 4;
#pragma unroll
    for (int fn = 0; fn < FMn; fn++) {
      int c = n0 + wn * (BM / WN) + fn * 16 + (lane & 15);
#pragma unroll
      for (int j = 0; j < 4; j++) {
        int r = r0 + j;
        size_t off = (size_t)r * 1024 + c;
        float v = acc[fm][fn][j];
        if (mode == 0 || mode == 6) {
          if (addF) v += addF[off];
        } else if (mode == 1) {
          v = c0 * (r == c ? 1.f : 0.f) + (addF ? c1 * addF[off] : 0.f) + c2 * v;
        } else if (mode == 2) {
          v = dc0 * (r == c ? 1.f : 0.f) + dc1 * addF[off] + dc2 * v;
        } else if (mode == 3) {
          v = 0.9f * addF[off] + 0.03125f * (v + addF2[off] * dvec[c]);
        }
        if (of) of[off] = v;
        if (outB) outB[off] = f2bf(v);
        acc[fm][fn][j] = v;
      }
    }
  }

  // optional transposed bf16 output (used by BM=64 NS X-updates only)
  if (outBT) {
    constexpr int LDT = BM + 1;
    __syncthreads();
#pragma unroll
    for (int fm = 0; fm < FMm; fm++) {
      int lr0 = wm * (BM / WM) + fm * 16 + (lane >> 4) * 4;
#pragma unroll
      for (int fn = 0; fn < FMn; fn++) {
        int lc = wn * (BM / WN) + fn * 16 + (lane & 15);
#pragma unroll
        for (int j = 0; j < 4; j++)
          lds[(lr0 + j) * LDT + lc] = f2bf(acc[fm][fn][j]);
      }
    }
    __syncthreads();
    for (int e = tid * 8; e < BM * BM; e += NT * 8) {
      int orr = e / BM;          // output row = col of tile
      int oc = e % BM;           // output col base = row of tile
      ushort8v w;
#pragma unroll
      for (int d = 0; d < 8; d++) w[d] = lds[(oc + d) * LDT + orr];
      *(ushort8v*)(outBT + (size_t)(n0 + orr) * 1024 + m0 + oc) = w;
    }
  }
}

// ---- reduce G: sum 16 partials over upper 128^2 tiles -> Gb bf16, mirror
// lower triangle, diag zeroed + gdiag. grid: dim3(16 subblocks, 36 tiles).
__global__ void __launch_bounds__(256) reduce_g_kernel(
    const float* __restrict__ P, unsigned short* __restrict__ Gb,
    float* __restrict__ gdiag) {
  int tt = blockIdx.y, ti = 0;
  while (tt >= 8 - ti) { tt -= 8 - ti; ++ti; }
  const int tj = ti + tt;
  const int eloc = (blockIdx.x * 256 + threadIdx.x) * 4;
  const int lr = eloc >> 7, lc = eloc & 127;
  const int r = ti * 128 + lr, c0 = tj * 128 + lc;
  const size_t off = (size_t)r * 1024 + c0;
  f32x4 s = *(const f32x4*)(P + off);
#pragma unroll
  for (int z = 1; z < 16; z++)
    s += *(const f32x4*)(P + ((size_t)z << 20) + off);
  ushort4v o;
#pragma unroll
  for (int q = 0; q < 4; q++) {
    int c = c0 + q;
    unsigned short b = f2bf(s[q]);
    if (ti == tj && c == r) { gdiag[r] = s[q]; o[q] = 0; }
    else o[q] = b;
    if (ti != tj) Gb[(size_t)c * 1024 + r] = b;  // mirror into lower triangle
  }
  *(ushort4v*)(Gb + off) = o;
}

// --- w = weight + 0.01*clip(trace,-1,1); atomic per-column sumsq (fused colfin)
__global__ void __launch_bounds__(256) wbuild_kernel(
    const float* __restrict__ weight, const float* __restrict__ tout,
    float* __restrict__ w, float* __restrict__ colsumsq) {
  int t = threadIdx.x, blk = blockIdx.x;
  float cs[4] = {0.f, 0.f, 0.f, 0.f};
  for (int r = 0; r < 64; r++) {
    size_t row = (size_t)blk * 64 + r;
    for (int cc = 0; cc < 4; cc++) {
      size_t idx = row * 1024 + cc * 256 + t;
      float u = tout[idx];
      u = fminf(fmaxf(u, -1.f), 1.f);
      float wv = weight[idx] + 0.01f * u;
      w[idx] = wv;
      cs[cc] += wv * wv;
    }
  }
  for (int cc = 0; cc < 4; cc++) atomicAdd(&colsumsq[cc * 256 + t], cs[cc]);
}

// --- X0 = w / max(colnorm,1e-3): writes Xf (f32), Xb (bf16), XbT (bf16^T)
// tile-based 64x64, fusing the old x0_kernel + transpose_kernel.
__global__ void __launch_bounds__(256) x0t_kernel(
    const float* __restrict__ w, const float* __restrict__ colsumsq,
    float* __restrict__ X, unsigned short* __restrict__ Xb,
    unsigned short* __restrict__ XbT) {
  __shared__ unsigned short tb[64][65];
  const int t = threadIdx.x;
  const int r0 = blockIdx.x * 64, c0 = blockIdx.y * 64;
#pragma unroll
  for (int p = 0; p < 2; p++) {
    int lr = p * 32 + (t >> 3);
    int lc = (t & 7) * 8;
    size_t base = (size_t)(r0 + lr) * 1024 + c0 + lc;
    f32x4 w0 = *(const f32x4*)(w + base);
    f32x4 w1 = *(const f32x4*)(w + base + 4);
    f32x4 s0 = *(const f32x4*)(colsumsq + c0 + lc);
    f32x4 s1 = *(const f32x4*)(colsumsq + c0 + lc + 4);
    f32x4 x0o, x1o; ushort8v xb;
#pragma unroll
    for (int d = 0; d < 4; d++) {
      x0o[d] = w0[d] / fmaxf(sqrtf(s0[d]), 1e-3f);
      x1o[d] = w1[d] / fmaxf(sqrtf(s1[d]), 1e-3f);
      xb[d] = f2bf(x0o[d]); xb[d + 4] = f2bf(x1o[d]);
      tb[lr][lc + d] = xb[d]; tb[lr][lc + 4 + d] = xb[d + 4];
    }
    *(f32x4*)(X + base) = x0o;
    *(f32x4*)(X + base + 4) = x1o;
    *(ushort8v*)(Xb + base) = xb;
  }
  __syncthreads();
#pragma unroll
  for (int p = 0; p < 2; p++) {
    int orr = p * 32 + (t >> 3);
    int oc = (t & 7) * 8;
    ushort8v o;
#pragma unroll
    for (int d = 0; d < 8; d++) o[d] = tb[oc + d][orr];
    *(ushort8v*)(XbT + (size_t)(c0 + orr) * 1024 + r0 + oc) = o;
  }
}

// ---------------- power-iteration init: v0 = +/-1 hash; zero norms ----------
__global__ void __launch_bounds__(256) pinit_kernel(
    float* __restrict__ v0, float* __restrict__ norms) {
  int i = blockIdx.x * 256 + threadIdx.x;
  unsigned h = (unsigned)i * 2654435761u;
  v0[i] = ((h >> 16) & 1u) ? 1.f : -1.f;
  if (blockIdx.x == 0 && threadIdx.x < 4) norms[threadIdx.x] = 0.f;
}

// ---------------- matvec: vout = A vin (A f32 1024x1024); ||vout||^2 += norm --
__global__ void __launch_bounds__(256) matvec_kernel(
    const float* __restrict__ A, const float* __restrict__ vin,
    float* __restrict__ vout, float* __restrict__ normsq) {
  __shared__ float red[4];
  int t = threadIdx.x;
  int r0 = blockIdx.x * 16;
  f32x4 vv = *(const f32x4*)(vin + t * 4);
  float sq = 0.f;
  for (int r = 0; r < 16; r++) {
    f32x4 a = *(const f32x4*)(A + (size_t)(r0 + r) * 1024 + t * 4);
    float d = a[0] * vv[0] + a[1] * vv[1] + a[2] * vv[2] + a[3] * vv[3];
    for (int m = 32; m; m >>= 1) d += __shfl_xor(d, m);
    if ((t & 63) == 0) red[t >> 6] = d;
    __syncthreads();
    if (t == 0) {
      float s = red[0] + red[1] + red[2] + red[3];
      vout[r0 + r] = s;
      sq += s * s;
    }
    __syncthreads();
  }
  if (t == 0) atomicAdd(normsq, sq);
}

// ---------------- quintic-1 coefficients from power-iter norms ----------------
__global__ void coefq_kernel(const float* __restrict__ norms,
                             float* __restrict__ dcoef) {
  const float QA = 3.4445f, QB = -4.7750f, QC = 2.0315f;
  float n1 = fmaxf(norms[1], 1e-30f), n2 = fmaxf(norms[2], 1e-30f);
  float lam = sqrtf(n2 / n1);            // ~ sigma_max^2
  float s = sqrtf(fmaxf(lam, 1e-8f)) / 0.95f;
  s = fmaxf(s, 1e-3f);
  float s2 = s * s;
  dcoef[0] = QA / s;
  dcoef[1] = QB / (s * s2);
  dcoef[2] = QC / (s * s2 * s2);
}

extern "C" void kernel_launch(void* const* d_in, const int* in_sizes, int n_in,
                              void* d_out, int out_size, void* d_ws, size_t ws_size,
                              hipStream_t stream) {
  const float* x      = (const float*)d_in[0];
  const float* weight = (const float*)d_in[1];
  const float* gamma  = (const float*)d_in[2];
  const float* beta   = (const float*)d_in[3];
  const float* trace  = (const float*)d_in[4];

  float* y_out = (float*)d_out;                  // [16384,1024]
  float* w_out = y_out + (size_t)16777216;       // [1024,1024]
  float* t_out = w_out + (size_t)1048576;        // [1024,1024]

  const size_t MB = 1048576;
  char* ws = (char*)d_ws;
  unsigned short* xn   = (unsigned short*)(ws);            // 32MB
  unsigned short* xnT  = (unsigned short*)(ws + 32 * MB);  // 32MB
  float* Xf0           = (float*)(ws + 64 * MB);           // 4MB
  float* Xf1           = (float*)(ws + 68 * MB);           // 4MB
  float* wbuf          = (float*)(ws + 72 * MB);           // 4MB (reused as Af)
  float* Af            = (float*)(ws + 72 * MB);           //   alias (wbuf dead)
  unsigned short* Xb0  = (unsigned short*)(ws + 76 * MB);  // 2MB
  unsigned short* Xb1  = (unsigned short*)(ws + 78 * MB);  // 2MB
  unsigned short* XbT0 = (unsigned short*)(ws + 80 * MB);  // 2MB
  unsigned short* XbT1 = (unsigned short*)(ws + 82 * MB);  // 2MB
  unsigned short* Ab   = (unsigned short*)(ws + 84 * MB);  // 2MB
  unsigned short* Rb   = (unsigned short*)(ws + 86 * MB);  // 2MB (also quintic B)
  unsigned short* Gb   = (unsigned short*)(ws + 88 * MB);  // 2MB
  unsigned short* wb   = (unsigned short*)(ws + 90 * MB);  // 2MB
  float* colsumsq      = (float*)(ws + 92 * MB);           // 4KB
  float* gdiag         = (float*)(ws + 92 * MB + 69632);   // 4KB
  float* vpow          = (float*)(ws + 92 * MB + 73728);   // 4 x 4KB (v0..v3)
  float* norms         = (float*)(ws + 92 * MB + 90112);   // 64B
  float* dcoef         = (float*)(ws + 92 * MB + 90176);   // 64B

  // G partials live in the (not yet written) y region of d_out: 16 x 4MB = 64MB
  float* P = y_out;

  // 1) LN -> xn ; transpose -> xnT ; weight -> bf16 (+ zero colsumsq)
  ln_kernel<<<16384, 256, 0, stream>>>(x, gamma, beta, xn);
  transpose_kernel<<<dim3(256, 16), 256, 0, stream>>>(xn, xnT, 16384, 1024);
  cvt_kernel<<<1024, 256, 0, stream>>>(weight, wb, colsumsq);

  // 2) G = xnT @ xnT^T symmetric: upper 36 tiles, K=16384 split-16 -> P
  //    flat 576 grid, XCD-slab mapping (mode 5); 8-wave blocks
  gemm_bt_kernel<128, 2, 4, 2, 1><<<dim3(576), 512, 0, stream>>>(
      xnT, xnT, nullptr, nullptr, nullptr, nullptr, P, nullptr, nullptr,
      16384, 1024, 5, 0.f, 0.f, 0.f);
  reduce_g_kernel<<<dim3(16, 36), 256, 0, stream>>>(P, Gb, gdiag);

  // 3) t_out = 0.9*trace + (1/32)*(W@G)  (diag of G corrected in f32)
  gemm_bt_kernel<64, 4, 2, 8, 2><<<dim3(16, 16), 512, 0, stream>>>(
      wb, Gb, trace, weight, gdiag, nullptr, t_out, nullptr, nullptr,
      1024, 1024, 3, 0.f, 0.f, 0.f);

  // 4) y = xn @ W^T (overwrites P region), XCD-swizzled flat grid; 8-wave
  gemm_bt_kernel<128, 2, 4, 2, 1><<<dim3(1024), 512, 0, stream>>>(
      xn, wb, nullptr, nullptr, nullptr, nullptr, y_out, nullptr, nullptr,
      1024, 1024, 6, 0.f, 0.f, 0.f);

  // 5) w-build (+atomic col norms) -> fused X0 (f32+bf16+bf16^T)
  wbuild_kernel<<<16, 256, 0, stream>>>(weight, t_out, wbuf, colsumsq);
  x0t_kernel<<<dim3(16, 16), 256, 0, stream>>>(wbuf, colsumsq, Xf0, Xb0, XbT0);

  // 6) A0 = X0^T X0 (f32 + bf16) ; power iteration for sigma_max
  gemm_bt_kernel<64, 4, 2, 8, 2><<<dim3(16, 16), 512, 0, stream>>>(
      XbT0, XbT0, nullptr, nullptr, nullptr, nullptr, Af, Ab, nullptr,
      1024, 1024, 0, 0.f, 0.f, 0.f);
  pinit_kernel<<<4, 256, 0, stream>>>(vpow, norms);
  matvec_kernel<<<64, 256, 0, stream>>>(Af, vpow, vpow + 1024, norms + 0);
  matvec_kernel<<<64, 256, 0, stream>>>(Af, vpow + 1024, vpow + 2048, norms + 1);
  matvec_kernel<<<64, 256, 0, stream>>>(Af, vpow + 2048, vpow + 3072, norms + 2);
  coefq_kernel<<<1, 1, 0, stream>>>(norms, dcoef);

  const float QA = 3.4445f, QB = -4.7750f, QC = 2.0315f;
  float* Xf[2] = {Xf0, Xf1};
  unsigned short* Xb[2] = {Xb0, Xb1};
  unsigned short* XbT[2] = {XbT0, XbT1};
  int cur = 0;

  // quintic 1 (scaled via device coeffs): B = dc0*I + dc1*A0 + dc2*A0^2 ; X <- X0@B
  gemm_bt_kernel<64, 4, 2, 8, 2><<<dim3(16, 16), 512, 0, stream>>>(
      Ab, Ab, Af, nullptr, nullptr, dcoef, nullptr, Rb, nullptr,
      1024, 1024, 2, 0.f, 0.f, 0.f);
  gemm_bt_kernel<64, 4, 2, 8, 2><<<dim3(16, 16), 512, 0, stream>>>(
      Xb[cur], Rb, nullptr, nullptr, nullptr, nullptr,
      Xf[cur ^ 1], Xb[cur ^ 1], XbT[cur ^ 1], 1024, 1024, 0, 0.f, 0.f, 0.f);
  cur ^= 1;

  // quintic 2,3: A = X^T X ; B = QA*I + QB*A + QC*A^2 ; X <- X@B
  for (int q = 0; q < 2; q++) {
    gemm_bt_kernel<64, 4, 2, 8, 2><<<dim3(16, 16), 512, 0, stream>>>(
        XbT[cur], XbT[cur], nullptr, nullptr, nullptr, nullptr, Af, Ab, nullptr,
        1024, 1024, 0, 0.f, 0.f, 0.f);
    gemm_bt_kernel<64, 4, 2, 8, 2><<<dim3(16, 16), 512, 0, stream>>>(
        Ab, Ab, Af, nullptr, nullptr, nullptr, nullptr, Rb, nullptr,
        1024, 1024, 1, QA, QB, QC);
    gemm_bt_kernel<64, 4, 2, 8, 2><<<dim3(16, 16), 512, 0, stream>>>(
        Xb[cur], Rb, nullptr, nullptr, nullptr, nullptr,
        Xf[cur ^ 1], Xb[cur ^ 1], XbT[cur ^ 1], 1024, 1024, 0, 0.f, 0.f, 0.f);
    cur ^= 1;
  }

  // cubic 1..3: R = 0.5*(I - X^T X) ; X <- X + X@R
  for (int t = 0; t < 3; t++) {
    gemm_bt_kernel<64, 4, 2, 8, 2><<<dim3(16, 16), 512, 0, stream>>>(
        XbT[cur], XbT[cur], nullptr, nullptr, nullptr, nullptr, nullptr, Rb,
        nullptr, 1024, 1024, 1, 0.5f, 0.f, -0.5f);
    bool last = (t == 2);
    gemm_bt_kernel<64, 4, 2, 8, 2><<<dim3(16, 16), 512, 0, stream>>>(
        Xb[cur], Rb, Xf[cur], nullptr, nullptr, nullptr,
        last ? w_out : Xf[cur ^ 1],
        last ? (unsigned short*)nullptr : Xb[cur ^ 1],
        last ? (unsigned short*)nullptr : XbT[cur ^ 1],
        1024, 1024, 0, 0.f, 0.f, 0.f);
    cur ^= 1;
  }
}

// Round 6
// 325.571 us; speedup vs baseline: 1.7738x; 1.1191x over previous
//
#include <hip/hip_runtime.h>

// EfficientHebbian on MI355X (gfx950) — round 9.
// Key change: k-interleaved bf16 operand storage (kperm within 64-groups) so
// each MFMA fragment is ONE ds_read_b128, conflict-free across all 32 banks
// (was 2x ds_read_b64 with structural 4-way conflicts = 22-31% of big-GEMM
// cycles). All bf16 operands are self-produced -> producers write kperm'd.
// Big GEMMs back to r7-proven 4-wave/256thr/DEPTH=2 (2 blk/CU).
// Small GEMMs: DEPTH=8,U=2, 512 thr, 128KB LDS ring.

typedef short short4v __attribute__((ext_vector_type(4)));
typedef short short8v __attribute__((ext_vector_type(8)));
typedef unsigned short ushort4v __attribute__((ext_vector_type(4)));
typedef unsigned short ushort8v __attribute__((ext_vector_type(8)));
typedef float f32x4 __attribute__((ext_vector_type(4)));

__device__ __forceinline__ unsigned short f2bf(float f) {
  union { float f; unsigned u; } v; v.f = f;
  unsigned r = 0x7fffu + ((v.u >> 16) & 1u);
  return (unsigned short)((v.u + r) >> 16);
}

// k-permutation within a 64-element group: natural k -> stored position.
// Stored 16B chunk c=(ks*4+g) holds natural {ks*32+g*4+[0,4), ks*32+g*4+16+[0,4)}
// = exactly one mfma_16x16x32 bf16 fragment per lane.
__device__ __forceinline__ int kperm(int t) {
  return (t & 32) + ((t >> 2) & 3) * 8 + ((t >> 4) & 1) * 4 + (t & 3);
}

__device__ __forceinline__ void gload_lds16(const void* g, void* l) {
  __builtin_amdgcn_global_load_lds(
      (const __attribute__((address_space(1))) void*)g,
      (__attribute__((address_space(3))) void*)l, 16, 0, 0);
}

// counted vmcnt wait; "memory" clobber = compiler fence for LDS/VMEM motion
__device__ __forceinline__ void waitvm(int n) {
  switch (n) {
    case 0: asm volatile("s_waitcnt vmcnt(0)" ::: "memory"); break;
    case 2: asm volatile("s_waitcnt vmcnt(2)" ::: "memory"); break;
    case 4: asm volatile("s_waitcnt vmcnt(4)" ::: "memory"); break;
    case 6: asm volatile("s_waitcnt vmcnt(6)" ::: "memory"); break;
    case 8: asm volatile("s_waitcnt vmcnt(8)" ::: "memory"); break;
    case 10: asm volatile("s_waitcnt vmcnt(10)" ::: "memory"); break;
    case 12: asm volatile("s_waitcnt vmcnt(12)" ::: "memory"); break;
    default: asm volatile("s_waitcnt vmcnt(0)" ::: "memory"); break;
  }
}

// ---------------- LayerNorm: x[row][1024] f32 -> xn bf16 (kperm'd) ----------
__global__ void __launch_bounds__(256) ln_kernel(
    const float* __restrict__ x, const float* __restrict__ gamma,
    const float* __restrict__ beta, unsigned short* __restrict__ xn) {
  __shared__ float sb[4];
  const int row = blockIdx.x;
  const int t = threadIdx.x;
  const float* xr = x + (size_t)row * 1024;
  f32x4 v = *(const f32x4*)(xr + t * 4);
  float s = v[0] + v[1] + v[2] + v[3];
  for (int m = 32; m; m >>= 1) s += __shfl_xor(s, m);
  if ((t & 63) == 0) sb[t >> 6] = s;
  __syncthreads();
  float mu = (sb[0] + sb[1] + sb[2] + sb[3]) * (1.0f / 1024.0f);
  __syncthreads();
  f32x4 d; float q = 0.f;
  for (int i = 0; i < 4; i++) { d[i] = v[i] - mu; q += d[i] * d[i]; }
  for (int m = 32; m; m >>= 1) q += __shfl_xor(q, m);
  if ((t & 63) == 0) sb[t >> 6] = q;
  __syncthreads();
  float var = (sb[0] + sb[1] + sb[2] + sb[3]) * (1.0f / 1024.0f);
  float rs = rsqrtf(var + 1e-5f);
  f32x4 g4 = *(const f32x4*)(gamma + t * 4);
  f32x4 b4 = *(const f32x4*)(beta + t * 4);
  ushort4v o;
  for (int i = 0; i < 4; i++) o[i] = f2bf(d[i] * rs * g4[i] + b4[i]);
  int col = t * 4;
  int sc = (col & ~63) + kperm(col & 63);
  *(ushort4v*)(xn + (size_t)row * 1024 + sc) = o;
}

// ------- f32 -> bf16 convert (kperm'd); block 0 also zeroes colsumsq -------
__global__ void __launch_bounds__(256) cvt_kernel(
    const float* __restrict__ in, unsigned short* __restrict__ out,
    float* __restrict__ zbuf) {
  if (blockIdx.x == 0) {
    f32x4 z = (f32x4){0.f, 0.f, 0.f, 0.f};
    ((f32x4*)zbuf)[threadIdx.x] = z;
  }
  size_t e = ((size_t)blockIdx.x * 256 + threadIdx.x) * 4;
  f32x4 v = *(const f32x4*)(in + e);
  ushort4v o;
  for (int k = 0; k < 4; k++) o[k] = f2bf(v[k]);
  int col = (int)(e & 1023);
  size_t sp = (e & ~(size_t)1023) + (col & ~63) + kperm(col & 63);
  *(ushort4v*)(out + sp) = o;
}

// -- bf16 transpose 64x64 tiles: in kperm'd rows -> out kperm'd rows ----------
__global__ void __launch_bounds__(256) transpose_kernel(
    const unsigned short* __restrict__ in, unsigned short* __restrict__ out,
    int R, int C) {
  __shared__ unsigned short tb[64][65];
  const int t = threadIdx.x;
  const int r0 = blockIdx.x * 64, c0 = blockIdx.y * 64;
#pragma unroll
  for (int p = 0; p < 2; p++) {
    int lr = p * 32 + (t >> 3);
    int lc = (t & 7) * 8;  // stored position within 64-group
    ushort8v v = *(const ushort8v*)(in + (size_t)(r0 + lr) * C + c0 + lc);
    int ch = lc >> 3;                         // stored chunk index
    int nb = (ch >> 2) * 32 + (ch & 3) * 4;   // natural base
#pragma unroll
    for (int d = 0; d < 4; d++) tb[lr][nb + d] = v[d];
#pragma unroll
    for (int d = 4; d < 8; d++) tb[lr][nb + 16 + d - 4] = v[d];
  }
  __syncthreads();
#pragma unroll
  for (int p = 0; p < 2; p++) {
    int orr = p * 32 + (t >> 3);
    int oc = (t & 7) * 8;  // natural token offset
    ushort4v w0, w1;
#pragma unroll
    for (int d = 0; d < 4; d++) { w0[d] = tb[oc + d][orr]; w1[d] = tb[oc + 4 + d][orr]; }
    unsigned short* orow = out + (size_t)(c0 + orr) * R + r0;
    *(ushort4v*)(orow + kperm(oc)) = w0;
    *(ushort4v*)(orow + kperm(oc + 4)) = w1;
  }
}

// ---------------- NT GEMM: C[M][N] = A[M][K] @ B[N][K]^T ----------------
// Operands stored kperm'd; fragment read = single ds_read_b128, conflict-free.
// BM x BM tile, BK=64, NK=16 K-steps, WM x WN waves. DEPTH-buffer ring,
// raw s_barrier + counted vmcnt, U tiles per barrier window.
// modes: 0: v=acc (+addF) ; 1: c0*I+c1*addF+c2*acc ; 2: dcoef variant
//        3: 0.9*addF + (1/32)*(acc + addF2*dvec[c])
//        5: symmetric-upper partial, XCD-slab map (flat 576 grid)
//        6: mode 0 with flat-grid XCD swizzle (M=128,N=8 tiles)
template <int BM, int WM, int WN, int DEPTH, int U>
__global__ void __launch_bounds__(WM * WN * 64, (WM * WN) / 2) gemm_bt_kernel(
    const unsigned short* __restrict__ A, const unsigned short* __restrict__ B,
    const float* __restrict__ addF, const float* __restrict__ addF2,
    const float* __restrict__ dvec, const float* __restrict__ dcoef,
    float* __restrict__ outF, unsigned short* __restrict__ outB,
    unsigned short* __restrict__ outBT,
    int ldk, int Kseg, int mode, float c0, float c1, float c2) {
  constexpr int WAVES = WM * WN;
  constexpr int NT = WAVES * 64;
  constexpr int FMm = BM / (16 * WM);
  constexpr int FMn = BM / (16 * WN);
  constexpr int CPW = BM / (8 * WAVES);  // 1KB chunks per wave per operand
  constexpr int L = 2 * CPW;             // vmem loads per wave per stage
  constexpr int BUFS = 2 * BM * 64;      // shorts per buffer (A then B)
  constexpr int NK = 16;                 // Kseg == 1024 always
  constexpr int NG = NK / U;
  __shared__ __align__(16) unsigned short lds[DEPTH * BUFS];
  const int tid = threadIdx.x, lane = tid & 63, wv = tid >> 6;
  const int wm = wv / WN, wn = wv % WN;

  int m0, n0, kb = 0, zseg = 0;
  if (mode == 5) {
    int id = blockIdx.x;
    int c = id & 7, s = id >> 3;
    zseg = c * 2 + (s >= 36 ? 1 : 0);
    int tt = (s >= 36) ? s - 36 : s;
    int ti = 0;
    while (tt >= 8 - ti) { tt -= 8 - ti; ++ti; }
    m0 = ti * BM; n0 = (ti + tt) * BM;
    kb = zseg * Kseg;
  } else if (mode == 6) {
    int l = blockIdx.x;
    int c = l & 7, s = l >> 3;
    m0 = (c * 16 + (s >> 3)) * BM;
    n0 = (s & 7) * BM;
  } else {
    m0 = blockIdx.x * BM; n0 = blockIdx.y * BM;
  }

  const int srow = lane >> 3;
  const int skoff = 8 * ((lane & 7) ^ srow);  // pre-swizzled global k-offset

  f32x4 acc[FMm][FMn];
  for (int a = 0; a < FMm; a++)
    for (int b = 0; b < FMn; b++) acc[a][b] = (f32x4){0.f, 0.f, 0.f, 0.f};

  auto stage = [&](int buf, int kk) {
#pragma unroll
    for (int ci = 0; ci < CPW; ci++) {
      int ch = wv * CPW + ci;
      const unsigned short* ga = A + (size_t)(m0 + 8 * ch + srow) * ldk + kk + skoff;
      const unsigned short* gb = B + (size_t)(n0 + 8 * ch + srow) * ldk + kk + skoff;
      char* lb = (char*)(lds + buf * BUFS);
      gload_lds16(ga, lb + ch * 1024);
      gload_lds16(gb, lb + BM * 128 + ch * 1024);
    }
  };

  // prologue: DEPTH-U stages in flight
#pragma unroll
  for (int d = 0; d < DEPTH - U; ++d) stage(d, kb + (d << 6));

#pragma unroll
  for (int g = 0; g < NG; ++g) {
    int done = U * g + U;                       // tiles that must be complete
    int issued = DEPTH - U + U * g;
    if (issued > NK) issued = NK;
    int ahead = issued - done;                  // stages allowed in flight
    waitvm(ahead * L);
    __builtin_amdgcn_s_barrier();
#pragma unroll
    for (int u = 0; u < U; ++u) {
      int ts = U * g + (DEPTH - U) + u;
      if (ts < NK) stage(ts % DEPTH, kb + (ts << 6));
    }

    const int g16 = lane >> 4;
#pragma unroll
    for (int u = 0; u < U; ++u) {
      const unsigned short* As = lds + ((U * g + u) % DEPTH) * BUFS;
      const unsigned short* Bs = As + BM * 64;
#pragma unroll
      for (int ks = 0; ks < 2; ks++) {
        short8v af[FMm], bfr[FMn];
        const int slot = (ks * 4 + g16) * 16;   // 16B chunk = full fragment
#pragma unroll
        for (int fm = 0; fm < FMm; fm++) {
          int row = wm * (BM / WM) + fm * 16 + (lane & 15);
          int swz = (row & 7) << 4;
          af[fm] = *(const short8v*)((const char*)As + row * 128 + (slot ^ swz));
        }
#pragma unroll
        for (int fn = 0; fn < FMn; fn++) {
          int row = wn * (BM / WN) + fn * 16 + (lane & 15);
          int swz = (row & 7) << 4;
          bfr[fn] = *(const short8v*)((const char*)Bs + row * 128 + (slot ^ swz));
        }
#pragma unroll
        for (int fm = 0; fm < FMm; fm++)
#pragma unroll
          for (int fn = 0; fn < FMn; fn++)
            acc[fm][fn] = __builtin_amdgcn_mfma_f32_16x16x32_bf16(
                af[fm], bfr[fn], acc[fm][fn], 0, 0, 0);
      }
    }
  }

  float* of = outF;
  if (mode == 5 && of) of += ((size_t)zseg << 20);
  float dc0 = 0.f, dc1 = 0.f, dc2 = 0.f;
  if (mode == 2) { dc0 = dcoef[0]; dc1 = dcoef[1]; dc2 = dcoef[2]; }

#pragma unroll
  for (int fm = 0; fm < FMm; fm++) {
    int r0 = m0 + wm * (BM / WM) + fm * 16 + (lane >> 4) * 4;
#pragma unroll
    for (int fn = 0; fn < FMn; fn++) {
      int c = n0 + wn * (BM / WN) + fn * 16 + (lane & 15);
      int cperm = (c & ~63) + kperm(c & 63);    // stored col for bf16 out
#pragma unroll
      for (int j = 0; j < 4; j++) {
        int r = r0 + j;
        size_t off = (size_t)r * 1024 + c;
        float v = acc[fm][fn][j];
        if (mode == 0 || mode == 6) {
          if (addF) v += addF[off];
        } else if (mode == 1) {
          v = c0 * (r == c ? 1.f : 0.f) + (addF ? c1 * addF[off] : 0.f) + c2 * v;
        } else if (mode == 2) {
          v = dc0 * (r == c ? 1.f : 0.f) + dc1 * addF[off] + dc2 * v;
        } else if (mode == 3) {
          v = 0.9f * addF[off] + 0.03125f * (v + addF2[off] * dvec[c]);
        }
        if (of) of[off] = v;
        if (outB) outB[(size_t)r * 1024 + cperm] = f2bf(v);
        acc[fm][fn][j] = v;
      }
    }
  }

  // optional transposed bf16 output (BM=64 NS X-updates only), kperm'd k-dim
  if (outBT) {
    constexpr int LDT = BM + 1;
    __syncthreads();
#pragma unroll
    for (int fm = 0; fm < FMm; fm++) {
      int lr0 = wm * (BM / WM) + fm * 16 + (lane >> 4) * 4;
#pragma unroll
      for (int fn = 0; fn < FMn; fn++) {
        int lc = wn * (BM / WN) + fn * 16 + (lane & 15);
#pragma unroll
        for (int j = 0; j < 4; j++)
          lds[(lr0 + j) * LDT + lc] = f2bf(acc[fm][fn][j]);
      }
    }
    __syncthreads();
    for (int e = tid * 8; e < BM * BM; e += NT * 8) {
      int orr = e / BM;          // output row = col of tile
      int oc = e % BM;           // natural k offset (row of tile), mult of 8
      ushort4v w0, w1;
#pragma unroll
      for (int d = 0; d < 4; d++) {
        w0[d] = lds[(oc + d) * LDT + orr];
        w1[d] = lds[(oc + 4 + d) * LDT + orr];
      }
      unsigned short* orow = outBT + (size_t)(n0 + orr) * 1024 + m0;
      *(ushort4v*)(orow + kperm(oc & 63)) = w0;
      *(ushort4v*)(orow + kperm((oc + 4) & 63)) = w1;
    }
  }
}

// ---- reduce G: sum 16 partials over upper 128^2 tiles -> Gb bf16 (kperm'd),
// mirror lower triangle, diag zeroed + gdiag. grid: dim3(16, 36 tiles).
__global__ void __launch_bounds__(256) reduce_g_kernel(
    const float* __restrict__ P, unsigned short* __restrict__ Gb,
    float* __restrict__ gdiag) {
  int tt = blockIdx.y, ti = 0;
  while (tt >= 8 - ti) { tt -= 8 - ti; ++ti; }
  const int tj = ti + tt;
  const int eloc = (blockIdx.x * 256 + threadIdx.x) * 4;
  const int lr = eloc >> 7, lc = eloc & 127;
  const int r = ti * 128 + lr, c0 = tj * 128 + lc;
  const size_t off = (size_t)r * 1024 + c0;
  f32x4 s = *(const f32x4*)(P + off);
#pragma unroll
  for (int z = 1; z < 16; z++)
    s += *(const f32x4*)(P + ((size_t)z << 20) + off);
  ushort4v o;
  const int rperm = (r & ~63) + kperm(r & 63);
#pragma unroll
  for (int q = 0; q < 4; q++) {
    int c = c0 + q;
    unsigned short b = f2bf(s[q]);
    if (ti == tj && c == r) { gdiag[r] = s[q]; o[q] = 0; }
    else o[q] = b;
    if (ti != tj) Gb[(size_t)c * 1024 + rperm] = b;  // mirror (kperm'd col)
  }
  *(ushort4v*)(Gb + (size_t)r * 1024 + (c0 & ~63) + kperm(c0 & 63)) = o;
}

// --- w = weight + 0.01*clip(trace,-1,1); atomic per-column sumsq -------------
__global__ void __launch_bounds__(256) wbuild_kernel(
    const float* __restrict__ weight, const float* __restrict__ tout,
    float* __restrict__ w, float* __restrict__ colsumsq) {
  int t = threadIdx.x, blk = blockIdx.x;
  float cs[4] = {0.f, 0.f, 0.f, 0.f};
  for (int r = 0; r < 64; r++) {
    size_t row = (size_t)blk * 64 + r;
    for (int cc = 0; cc < 4; cc++) {
      size_t idx = row * 1024 + cc * 256 + t;
      float u = tout[idx];
      u = fminf(fmaxf(u, -1.f), 1.f);
      float wv = weight[idx] + 0.01f * u;
      w[idx] = wv;
      cs[cc] += wv * wv;
    }
  }
  for (int cc = 0; cc < 4; cc++) atomicAdd(&colsumsq[cc * 256 + t], cs[cc]);
}

// --- X0 = w / max(colnorm,1e-3): writes Xf (f32), Xb (bf16 kperm'd),
// XbT (bf16 kperm'd k-dim). tile-based 64x64.
__global__ void __launch_bounds__(256) x0t_kernel(
    const float* __restrict__ w, const float* __restrict__ colsumsq,
    float* __restrict__ X, unsigned short* __restrict__ Xb,
    unsigned short* __restrict__ XbT) {
  __shared__ unsigned short tb[64][65];
  const int t = threadIdx.x;
  const int r0 = blockIdx.x * 64, c0 = blockIdx.y * 64;
#pragma unroll
  for (int p = 0; p < 2; p++) {
    int lr = p * 32 + (t >> 3);
    int lc = (t & 7) * 8;  // natural col offset
    size_t base = (size_t)(r0 + lr) * 1024 + c0 + lc;
    f32x4 w0 = *(const f32x4*)(w + base);
    f32x4 w1 = *(const f32x4*)(w + base + 4);
    f32x4 s0 = *(const f32x4*)(colsumsq + c0 + lc);
    f32x4 s1 = *(const f32x4*)(colsumsq + c0 + lc + 4);
    f32x4 x0o, x1o; ushort4v xb0, xb1;
#pragma unroll
    for (int d = 0; d < 4; d++) {
      x0o[d] = w0[d] / fmaxf(sqrtf(s0[d]), 1e-3f);
      x1o[d] = w1[d] / fmaxf(sqrtf(s1[d]), 1e-3f);
      xb0[d] = f2bf(x0o[d]); xb1[d] = f2bf(x1o[d]);
      tb[lr][lc + d] = xb0[d]; tb[lr][lc + 4 + d] = xb1[d];
    }
    *(f32x4*)(X + base) = x0o;
    *(f32x4*)(X + base + 4) = x1o;
    unsigned short* xrow = Xb + (size_t)(r0 + lr) * 1024 + c0;
    *(ushort4v*)(xrow + kperm(lc)) = xb0;
    *(ushort4v*)(xrow + kperm(lc + 4)) = xb1;
  }
  __syncthreads();
#pragma unroll
  for (int p = 0; p < 2; p++) {
    int orr = p * 32 + (t >> 3);
    int oc = (t & 7) * 8;  // natural row offset (k-dim of XbT)
    ushort4v w0, w1;
#pragma unroll
    for (int d = 0; d < 4; d++) { w0[d] = tb[oc + d][orr]; w1[d] = tb[oc + 4 + d][orr]; }
    unsigned short* orow = XbT + (size_t)(c0 + orr) * 1024 + r0;
    *(ushort4v*)(orow + kperm(oc)) = w0;
    *(ushort4v*)(orow + kperm(oc + 4)) = w1;
  }
}

// ---------------- power-iteration init: v0 = +/-1 hash; zero norms ----------
__global__ void __launch_bounds__(256) pinit_kernel(
    float* __restrict__ v0, float* __restrict__ norms) {
  int i = blockIdx.x * 256 + threadIdx.x;
  unsigned h = (unsigned)i * 2654435761u;
  v0[i] = ((h >> 16) & 1u) ? 1.f : -1.f;
  if (blockIdx.x == 0 && threadIdx.x < 4) norms[threadIdx.x] = 0.f;
}

// ---------------- matvec: vout = A vin (A f32 1024x1024); ||vout||^2 += norm --
__global__ void __launch_bounds__(256) matvec_kernel(
    const float* __restrict__ A, const float* __restrict__ vin,
    float* __restrict__ vout, float* __restrict__ normsq) {
  __shared__ float red[4];
  int t = threadIdx.x;
  int r0 = blockIdx.x * 16;
  f32x4 vv = *(const f32x4*)(vin + t * 4);
  float sq = 0.f;
  for (int r = 0; r < 16; r++) {
    f32x4 a = *(const f32x4*)(A + (size_t)(r0 + r) * 1024 + t * 4);
    float d = a[0] * vv[0] + a[1] * vv[1] + a[2] * vv[2] + a[3] * vv[3];
    for (int m = 32; m; m >>= 1) d += __shfl_xor(d, m);
    if ((t & 63) == 0) red[t >> 6] = d;
    __syncthreads();
    if (t == 0) {
      float s = red[0] + red[1] + red[2] + red[3];
      vout[r0 + r] = s;
      sq += s * s;
    }
    __syncthreads();
  }
  if (t == 0) atomicAdd(normsq, sq);
}

// ---------------- quintic-1 coefficients from power-iter norms ----------------
__global__ void coefq_kernel(const float* __restrict__ norms,
                             float* __restrict__ dcoef) {
  const float QA = 3.4445f, QB = -4.7750f, QC = 2.0315f;
  float n1 = fmaxf(norms[1], 1e-30f), n2 = fmaxf(norms[2], 1e-30f);
  float lam = sqrtf(n2 / n1);            // ~ sigma_max^2
  float s = sqrtf(fmaxf(lam, 1e-8f)) / 0.95f;
  s = fmaxf(s, 1e-3f);
  float s2 = s * s;
  dcoef[0] = QA / s;
  dcoef[1] = QB / (s * s2);
  dcoef[2] = QC / (s * s2 * s2);
}

extern "C" void kernel_launch(void* const* d_in, const int* in_sizes, int n_in,
                              void* d_out, int out_size, void* d_ws, size_t ws_size,
                              hipStream_t stream) {
  const float* x      = (const float*)d_in[0];
  const float* weight = (const float*)d_in[1];
  const float* gamma  = (const float*)d_in[2];
  const float* beta   = (const float*)d_in[3];
  const float* trace  = (const float*)d_in[4];

  float* y_out = (float*)d_out;                  // [16384,1024]
  float* w_out = y_out + (size_t)16777216;       // [1024,1024]
  float* t_out = w_out + (size_t)1048576;        // [1024,1024]

  const size_t MB = 1048576;
  char* ws = (char*)d_ws;
  unsigned short* xn   = (unsigned short*)(ws);            // 32MB
  unsigned short* xnT  = (unsigned short*)(ws + 32 * MB);  // 32MB
  float* Xf0           = (float*)(ws + 64 * MB);           // 4MB
  float* Xf1           = (float*)(ws + 68 * MB);           // 4MB
  float* wbuf          = (float*)(ws + 72 * MB);           // 4MB (reused as Af)
  float* Af            = (float*)(ws + 72 * MB);           //   alias (wbuf dead)
  unsigned short* Xb0  = (unsigned short*)(ws + 76 * MB);  // 2MB
  unsigned short* Xb1  = (unsigned short*)(ws + 78 * MB);  // 2MB
  unsigned short* XbT0 = (unsigned short*)(ws + 80 * MB);  // 2MB
  unsigned short* XbT1 = (unsigned short*)(ws + 82 * MB);  // 2MB
  unsigned short* Ab   = (unsigned short*)(ws + 84 * MB);  // 2MB
  unsigned short* Rb   = (unsigned short*)(ws + 86 * MB);  // 2MB (also quintic B)
  unsigned short* Gb   = (unsigned short*)(ws + 88 * MB);  // 2MB
  unsigned short* wb   = (unsigned short*)(ws + 90 * MB);  // 2MB
  float* colsumsq      = (float*)(ws + 92 * MB);           // 4KB
  float* gdiag         = (float*)(ws + 92 * MB + 69632);   // 4KB
  float* vpow          = (float*)(ws + 92 * MB + 73728);   // 4 x 4KB (v0..v3)
  float* norms         = (float*)(ws + 92 * MB + 90112);   // 64B
  float* dcoef         = (float*)(ws + 92 * MB + 90176);   // 64B

  // G partials live in the (not yet written) y region of d_out: 16 x 4MB = 64MB
  float* P = y_out;

  // 1) LN -> xn ; transpose -> xnT ; weight -> bf16 (+ zero colsumsq)
  ln_kernel<<<16384, 256, 0, stream>>>(x, gamma, beta, xn);
  transpose_kernel<<<dim3(256, 16), 256, 0, stream>>>(xn, xnT, 16384, 1024);
  cvt_kernel<<<1024, 256, 0, stream>>>(weight, wb, colsumsq);

  // 2) G = xnT @ xnT^T symmetric: upper 36 tiles, K=16384 split-16 -> P
  //    flat 576 grid, XCD-slab mapping (mode 5); 4-wave blocks (r7 config)
  gemm_bt_kernel<128, 2, 2, 2, 1><<<dim3(576), 256, 0, stream>>>(
      xnT, xnT, nullptr, nullptr, nullptr, nullptr, P, nullptr, nullptr,
      16384, 1024, 5, 0.f, 0.f, 0.f);
  reduce_g_kernel<<<dim3(16, 36), 256, 0, stream>>>(P, Gb, gdiag);

  // 3) t_out = 0.9*trace + (1/32)*(W@G)  (diag of G corrected in f32)
  gemm_bt_kernel<64, 4, 2, 8, 2><<<dim3(16, 16), 512, 0, stream>>>(
      wb, Gb, trace, weight, gdiag, nullptr, t_out, nullptr, nullptr,
      1024, 1024, 3, 0.f, 0.f, 0.f);

  // 4) y = xn @ W^T (overwrites P region), XCD-swizzled flat grid; 4-wave
  gemm_bt_kernel<128, 2, 2, 2, 1><<<dim3(1024), 256, 0, stream>>>(
      xn, wb, nullptr, nullptr, nullptr, nullptr, y_out, nullptr, nullptr,
      1024, 1024, 6, 0.f, 0.f, 0.f);

  // 5) w-build (+atomic col norms) -> fused X0 (f32+bf16+bf16^T)
  wbuild_kernel<<<16, 256, 0, stream>>>(weight, t_out, wbuf, colsumsq);
  x0t_kernel<<<dim3(16, 16), 256, 0, stream>>>(wbuf, colsumsq, Xf0, Xb0, XbT0);

  // 6) A0 = X0^T X0 (f32 + bf16) ; power iteration for sigma_max
  gemm_bt_kernel<64, 4, 2, 8, 2><<<dim3(16, 16), 512, 0, stream>>>(
      XbT0, XbT0, nullptr, nullptr, nullptr, nullptr, Af, Ab, nullptr,
      1024, 1024, 0, 0.f, 0.f, 0.f);
  pinit_kernel<<<4, 256, 0, stream>>>(vpow, norms);
  matvec_kernel<<<64, 256, 0, stream>>>(Af, vpow, vpow + 1024, norms + 0);
  matvec_kernel<<<64, 256, 0, stream>>>(Af, vpow + 1024, vpow + 2048, norms + 1);
  matvec_kernel<<<64, 256, 0, stream>>>(Af, vpow + 2048, vpow + 3072, norms + 2);
  coefq_kernel<<<1, 1, 0, stream>>>(norms, dcoef);

  const float QA = 3.4445f, QB = -4.7750f, QC = 2.0315f;
  float* Xf[2] = {Xf0, Xf1};
  unsigned short* Xb[2] = {Xb0, Xb1};
  unsigned short* XbT[2] = {XbT0, XbT1};
  int cur = 0;

  // quintic 1 (scaled via device coeffs): B = dc0*I + dc1*A0 + dc2*A0^2 ; X <- X0@B
  gemm_bt_kernel<64, 4, 2, 8, 2><<<dim3(16, 16), 512, 0, stream>>>(
      Ab, Ab, Af, nullptr, nullptr, dcoef, nullptr, Rb, nullptr,
      1024, 1024, 2, 0.f, 0.f, 0.f);
  gemm_bt_kernel<64, 4, 2, 8, 2><<<dim3(16, 16), 512, 0, stream>>>(
      Xb[cur], Rb, nullptr, nullptr, nullptr, nullptr,
      Xf[cur ^ 1], Xb[cur ^ 1], XbT[cur ^ 1], 1024, 1024, 0, 0.f, 0.f, 0.f);
  cur ^= 1;

  // quintic 2,3: A = X^T X ; B = QA*I + QB*A + QC*A^2 ; X <- X@B
  for (int q = 0; q < 2; q++) {
    gemm_bt_kernel<64, 4, 2, 8, 2><<<dim3(16, 16), 512, 0, stream>>>(
        XbT[cur], XbT[cur], nullptr, nullptr, nullptr, nullptr, Af, Ab, nullptr,
        1024, 1024, 0, 0.f, 0.f, 0.f);
    gemm_bt_kernel<64, 4, 2, 8, 2><<<dim3(16, 16), 512, 0, stream>>>(
        Ab, Ab, Af, nullptr, nullptr, nullptr, nullptr, Rb, nullptr,
        1024, 1024, 1, QA, QB, QC);
    gemm_bt_kernel<64, 4, 2, 8, 2><<<dim3(16, 16), 512, 0, stream>>>(
        Xb[cur], Rb, nullptr, nullptr, nullptr, nullptr,
        Xf[cur ^ 1], Xb[cur ^ 1], XbT[cur ^ 1], 1024, 1024, 0, 0.f, 0.f, 0.f);
    cur ^= 1;
  }

  // cubic 1..3: R = 0.5*(I - X^T X) ; X <- X + X@R
  for (int t = 0; t < 3; t++) {
    gemm_bt_kernel<64, 4, 2, 8, 2><<<dim3(16, 16), 512, 0, stream>>>(
        XbT[cur], XbT[cur], nullptr, nullptr, nullptr, nullptr, nullptr, Rb,
        nullptr, 1024, 1024, 1, 0.5f, 0.f, -0.5f);
    bool last = (t == 2);
    gemm_bt_kernel<64, 4, 2, 8, 2><<<dim3(16, 16), 512, 0, stream>>>(
        Xb[cur], Rb, Xf[cur], nullptr, nullptr, nullptr,
        last ? w_out : Xf[cur ^ 1],
        last ? (unsigned short*)nullptr : Xb[cur ^ 1],
        last ? (unsigned short*)nullptr : XbT[cur ^ 1],
        1024, 1024, 0, 0.f, 0.f, 0.f);
    cur ^= 1;
  }
}